// Round 9
// baseline (214.508 us; speedup 1.0000x reference)
//
#include <hip/hip_runtime.h>
#include <float.h>
#include <math.h>

// NNConv net: 2x edge-conditioned conv (scalar edge attr) + 2 FC + log_softmax.
// W_e = a_e*U_s + V_s over <=26 breakpoint segments of the scalar edge attr.
// Edges bucketed by segment (chunk-aligned so a wave chunk is single-segment).
// R7: tail 4-nodes/wave loop-order reuse -> 198 us. R8/R9: cooperative fusion
// FALSIFIED (997 us). R10: float4 inner-loop x loads spilled Ur/Vr (edge2 94 us).
// R11: prep fusion {fill,build_uv,assign_hist} + scatter-with-folded-scan +
//      512B memset + R7 edge bodies -> 189.7 us.
// R12: LDS x-row staging in edge1/edge2: per-chunk cooperative float4 gather of
//      src rows into 8 KB LDS (prologue, temps die at ds_write -> no inner-loop
//      VGPR pressure like R10), inner loop reads x via static-offset LDS
//      broadcasts. Kills the 16-deep serial readlane->s_load chain.

#define NCONST 25
#define CH1 32   // edges per wave chunk, conv1
#define CH2 16   // edges per wave chunk, conv2
#define PACK_MASK 0x1FFFF  // edge id < 2^17 (E = 100000)
#define TNB 4    // nodes per wave in tail
#define K1_FILL 64
#define K1_UV   260

__device__ __forceinline__ void atomicMaxFloat(float* addr, float val) {
    if (val >= 0.f) atomicMax((int*)addr, __float_as_int(val));
    else            atomicMin((unsigned int*)addr, __float_as_uint(val));
}
__device__ __forceinline__ float readlane_f(float v, int l) {
    return __int_as_float(__builtin_amdgcn_readlane(__float_as_int(v), l));
}
__device__ __forceinline__ float elu_f(float a) {
    return a > 0.f ? a : expm1f(a);
}

struct PrepParams {
    const float *ea;
    const float *w1a, *b1a, *w1b, *b1b;
    const float *w2a, *b2a, *w2b, *b2b;
    int *hist, *segp, *ord1;               // ord1/ord2 contiguous; fill covers both
    float *U1, *V1, *U2, *V2, *AGG1;       // AGG1/AGG2 contiguous
    int N, E, capSum;
};

// ===== K1: fused {fill aggs/ords, build_uv, assign_hist}. Block role by
// blockIdx range; sections mutually independent (hist pre-zeroed by memset).
__global__ void prep_kernel(PrepParams p) {
    __shared__ float t1[NCONST], t2[NCONST];
    __shared__ int lh[64];
    __shared__ float swa[NCONST], sba[NCONST], stt[NCONST];
    __shared__ int srk[NCONST];
    __shared__ unsigned msk_sh;
    const int bid = blockIdx.x, tid = threadIdx.x;

    if (bid < K1_FILL) {
        int nAgg = p.N * 96, total = nAgg + p.capSum;
        for (int i = bid * 256 + tid; i < total; i += K1_FILL * 256) {
            if (i < nAgg) p.AGG1[i] = -FLT_MAX;
            else p.ord1[i - nAgg] = -1;
        }
    } else if (bid < K1_FILL + K1_UV) {
        int v = bid - K1_FILL;
        int seg = v / 10;
        int bx  = v % 10;
        int conv = (bx < 2) ? 0 : 1;
        const float* wa = conv ? p.w2a : p.w1a;
        const float* ba = conv ? p.b2a : p.b1a;
        if (tid < NCONST) {
            float w = wa[tid], b = ba[tid];
            swa[tid] = w; sba[tid] = b;
            stt[tid] = (w != 0.f) ? (-b / w) : INFINITY;
        }
        __syncthreads();
        if (tid < NCONST) {
            int rk = 0;
            for (int l = 0; l < NCONST; ++l) rk += (stt[l] < stt[tid]) ? 1 : 0;
            srk[tid] = rk;
        }
        __syncthreads();
        if (tid == 0) {
            unsigned m = 0;
            for (int k = 0; k < NCONST; ++k) {
                float w = swa[k];
                bool act = (w > 0.f) ? (seg > srk[k])
                         : (w < 0.f) ? (seg <= srk[k])
                                     : (sba[k] > 0.f);
                if (act) m |= (1u << k);
            }
            msk_sh = m;
        }
        __syncthreads();
        unsigned msk = msk_sh;
        if (conv == 0) {
            int idx = bx * 256 + tid;           // < 512
            float u = 0.f, vv = 0.f;
            for (int k = 0; k < NCONST; ++k)
                if (msk & (1u << k)) { float w = p.w1b[k * 512 + idx]; u = fmaf(swa[k], w, u); vv = fmaf(sba[k], w, vv); }
            vv += p.b1b[idx];
            p.U1[seg * 512 + idx] = u; p.V1[seg * 512 + idx] = vv;
        } else {
            int idx = (bx - 2) * 256 + tid;     // < 2048
            float u = 0.f, vv = 0.f;
            for (int k = 0; k < NCONST; ++k)
                if (msk & (1u << k)) { float w = p.w2b[k * 2048 + idx]; u = fmaf(swa[k], w, u); vv = fmaf(sba[k], w, vv); }
            vv += p.b2b[idx];
            p.U2[seg * 2048 + idx] = u; p.V2[seg * 2048 + idx] = vv;
        }
    } else {
        if (tid < NCONST) {
            float w = p.w1a[tid]; t1[tid] = (w != 0.f) ? (-p.b1a[tid] / w) : INFINITY;
            float v = p.w2a[tid]; t2[tid] = (v != 0.f) ? (-p.b2a[tid] / v) : INFINITY;
        }
        if (tid < 64) lh[tid] = 0;
        __syncthreads();
        int e = (bid - K1_FILL - K1_UV) * 256 + tid;
        if (e < p.E) {
            float a = p.ea[e];
            int j1 = 0, j2 = 0;
            for (int k = 0; k < NCONST; ++k) { j1 += (t1[k] < a); j2 += (t2[k] < a); }
            p.segp[e] = j1 | (j2 << 8);
            atomicAdd(&lh[j1], 1); atomicAdd(&lh[32 + j2], 1);
        }
        __syncthreads();
        if (tid < 64 && lh[tid]) atomicAdd(&p.hist[tid], lh[tid]);
    }
}

// ===== K2: scatter with in-block scan (scanpad folded in).
__global__ void scatter_scan_kernel(const int* __restrict__ segpack, int E,
                                    const int* __restrict__ hist, int* __restrict__ cur,
                                    int* __restrict__ order1, int* __restrict__ order2) {
    __shared__ int h[64], sbase[64], lh[64], lb[64];
    int tid = threadIdx.x;
    if (tid < 64) h[tid] = hist[tid];
    __syncthreads();
    if (tid == 0) {
        int off = 0;
        for (int j = 0; j < 26; ++j) { sbase[j] = off; off += ((h[j] + CH1 - 1) / CH1) * CH1; }
    } else if (tid == 1) {
        int off = 0;
        for (int j = 0; j < 26; ++j) { sbase[32 + j] = off; off += ((h[32 + j] + CH2 - 1) / CH2) * CH2; }
    }
    if (tid < 64) lh[tid] = 0;
    __syncthreads();
    int e = blockIdx.x * 256 + tid;
    bool valid = e < E;
    int j1 = 0, j2 = 0, r1 = 0, r2 = 0;
    if (valid) {
        int pk = segpack[e]; j1 = pk & 0xFF; j2 = pk >> 8;
        r1 = atomicAdd(&lh[j1], 1); r2 = atomicAdd(&lh[32 + j2], 1);
    }
    __syncthreads();
    if (tid < 64 && lh[tid]) lb[tid] = sbase[tid] + atomicAdd(&cur[tid], lh[tid]);
    __syncthreads();
    if (valid) {
        order1[lb[j1] + r1] = (j1 << 17) | e;
        order2[lb[32 + j2] + r2] = (j2 << 17) | e;
    }
}

// ===== edge1: IC=16, OC=32, half-wave per edge (2 edges/iter).
// R12: 32 src rows (16 floats each) staged into LDS per chunk; inner loop
// reads x via static-offset LDS broadcasts (half-waves hit disjoint banks).
__global__ void edge1_kernel(const float* __restrict__ xin, const int* __restrict__ src,
                             const int* __restrict__ tgt, const float* __restrict__ ea,
                             const int* __restrict__ order, int cap,
                             const float* __restrict__ U, const float* __restrict__ V,
                             float* __restrict__ agg) {
    __shared__ __align__(16) float xsh[4][CH1][16];   // 8 KB/block
    int wvb = threadIdx.x >> 6;
    int wid = (blockIdx.x * blockDim.x + threadIdx.x) >> 6;
    int lane = threadIdx.x & 63;
    int base = wid * CH1;
    if (base >= cap) return;
    int pk = order[base + (lane & (CH1 - 1))];
    int p0 = __builtin_amdgcn_readfirstlane(pk);
    if (p0 < 0) return;                        // whole-pad chunk past used region
    int seg = p0 >> 17;
    int ev = (pk < 0) ? 0 : (pk & PACK_MASK);
    int sv = src[ev], tv = tgt[ev];
    float av = ea[ev];
    int half = lane >> 5, c = lane & 31;
    // stage 32 rows x 16 floats: row r = lane>>1, 2 lanes/row, 2 float4 each
    {
        int r = lane >> 1, part = lane & 1;
        int sr = __shfl(sv, r, 64);
        const float4* xrow = (const float4*)(xin + (size_t)sr * 16);
        float4 v0 = xrow[part];
        float4 v1 = xrow[part + 2];
        float4* dst = (float4*)xsh[wvb][r];
        dst[part] = v0;
        dst[part + 2] = v1;
    }
    float Ur[16], Vr[16];
    {
        const float* Us = U + seg * 512 + c;
        const float* Vs = V + seg * 512 + c;
#pragma unroll
        for (int i = 0; i < 16; ++i) { Ur[i] = Us[i * 32]; Vr[i] = Vs[i * 32]; }
    }
    // no barrier: staging and consumption are same-wave (compiler waits lgkmcnt)
#pragma unroll
    for (int t = 0; t < CH1; t += 2) {
        int pA = __builtin_amdgcn_readlane(pk, t);
        int pB = __builtin_amdgcn_readlane(pk, t + 1);
        int tA = __builtin_amdgcn_readlane(tv, t);
        int tB = __builtin_amdgcn_readlane(tv, t + 1);
        float aA = readlane_f(av, t);
        float aB = readlane_f(av, t + 1);
        float ah = half ? aB : aA;
        int   th = half ? tB : tA;
        int   ph = half ? pB : pA;
        const float* xh = xsh[wvb][t + half];
        float acc = 0.f;
#pragma unroll
        for (int i = 0; i < 16; ++i)
            acc = fmaf(xh[i], fmaf(ah, Ur[i], Vr[i]), acc);
        if (ph >= 0) atomicMaxFloat(&agg[th * 32 + c], acc);
    }
}

// ===== edge2: IC=32, OC=64, lane = out channel, A/B edge pair.
// R12: 16 src rows (32 floats each) staged into LDS; inner loop reads x via
// whole-wave LDS broadcasts (static offsets -> no VGPR address pressure).
__global__ void edge2_kernel(const float* __restrict__ xin, const int* __restrict__ src,
                             const int* __restrict__ tgt, const float* __restrict__ ea,
                             const int* __restrict__ order, int cap,
                             const float* __restrict__ U, const float* __restrict__ V,
                             float* __restrict__ agg) {
    __shared__ __align__(16) float xsh[4][CH2][32];   // 8 KB/block
    int wvb = threadIdx.x >> 6;
    int wid = (blockIdx.x * blockDim.x + threadIdx.x) >> 6;
    int lane = threadIdx.x & 63;
    int base = wid * CH2;
    if (base >= cap) return;
    int pk = order[base + (lane & (CH2 - 1))];
    int p0 = __builtin_amdgcn_readfirstlane(pk);
    if (p0 < 0) return;
    int seg = p0 >> 17;
    int ev = (pk < 0) ? 0 : (pk & PACK_MASK);
    int sv = src[ev], tv = tgt[ev];
    float av = ea[ev];
    // stage 16 rows x 32 floats: row r = lane>>2, 4 lanes/row, 2 float4 each
    {
        int r = lane >> 2, part = lane & 3;
        int sr = __shfl(sv, r, 64);
        const float4* xrow = (const float4*)(xin + (size_t)sr * 32);
        float4 v0 = xrow[part];
        float4 v1 = xrow[part + 4];
        float4* dst = (float4*)xsh[wvb][r];
        dst[part] = v0;
        dst[part + 4] = v1;
    }
    float Ur[32], Vr[32];
    {
        const float* Us = U + seg * 2048 + lane;
        const float* Vs = V + seg * 2048 + lane;
#pragma unroll
        for (int i = 0; i < 32; ++i) { Ur[i] = Us[i * 64]; Vr[i] = Vs[i * 64]; }
    }
    // no barrier: same-wave staging/consumption
#pragma unroll
    for (int t = 0; t < CH2; t += 2) {
        int pA = __builtin_amdgcn_readlane(pk, t);
        int pB = __builtin_amdgcn_readlane(pk, t + 1);
        int tA = __builtin_amdgcn_readlane(tv, t);
        int tB = __builtin_amdgcn_readlane(tv, t + 1);
        float aA = readlane_f(av, t);
        float aB = readlane_f(av, t + 1);
        const float* xA = xsh[wvb][t];
        const float* xB = xsh[wvb][t + 1];
        float accA = 0.f, accB = 0.f;
#pragma unroll
        for (int i = 0; i < 32; ++i) {
            accA = fmaf(xA[i], fmaf(aA, Ur[i], Vr[i]), accA);
            accB = fmaf(xB[i], fmaf(aB, Ur[i], Vr[i]), accB);
        }
        if (pA >= 0) atomicMaxFloat(&agg[tA * 64 + lane], accA);
        if (pB >= 0) atomicMaxFloat(&agg[tB * 64 + lane], accB);
    }
}

// ===== node1: out = elu( fixup(agg) + x @ wr1 + bias1 ). R7 body.
__global__ void node1_kernel(const float* __restrict__ xin, const float* __restrict__ agg,
                             const float* __restrict__ wroot, const float* __restrict__ bias,
                             float* __restrict__ out, int N) {
    int idx = blockIdx.x * blockDim.x + threadIdx.x;
    if (idx >= N * 32) return;
    int n = idx >> 5, c = idx & 31;
    float v = agg[idx];
    if (v == -FLT_MAX) v = 0.f;
    float acc = v + bias[c];
#pragma unroll
    for (int i = 0; i < 16; ++i) acc = fmaf(xin[n * 16 + i], wroot[i * 32 + c], acc);
    out[idx] = acc > 0.f ? acc : expm1f(acc);
}

// ===== tail: node2 + fc1 + fc2 + log_softmax. R7 body: 4 nodes/wave, zero
// local arrays (allocator pins 64-VGPR budget; register arrays spill).
__global__ void tail_kernel(const float* __restrict__ h1, const float* __restrict__ agg2,
                            const float* __restrict__ wr2, const float* __restrict__ bias2,
                            const float* __restrict__ fc1w, const float* __restrict__ fc1b,
                            const float* __restrict__ fc2w, const float* __restrict__ fc2b,
                            float* __restrict__ out) {
    __shared__ __align__(16) float h1sh[4][TNB][32];
    __shared__ __align__(16) float h2sh[4][TNB][64];
    __shared__ __align__(16) float h3sh[4][TNB][132];   // +4 pad
    __shared__ __align__(16) float wTsh[10][132];       // fc2w transposed
    int tid = threadIdx.x;
    int wv = tid >> 6, lane = tid & 63;

    for (int t = tid; t < 1280; t += 256) {
        int k = t / 10, j = t - k * 10;
        wTsh[j][k] = fc2w[t];
    }
    __syncthreads();   // only barrier; everything below is wave-local

    int nb = blockIdx.x * (4 * TNB) + wv * TNB;

    {
        const float2* hp = (const float2*)(h1 + (size_t)nb * 32);
        ((float2*)&h1sh[wv][0][0])[lane] = hp[lane];
    }

    float b2v = bias2[lane];
    float ac0 = agg2[(size_t)(nb + 0) * 64 + lane];
    float ac1 = agg2[(size_t)(nb + 1) * 64 + lane];
    float ac2 = agg2[(size_t)(nb + 2) * 64 + lane];
    float ac3 = agg2[(size_t)(nb + 3) * 64 + lane];
    ac0 = (ac0 == -FLT_MAX ? 0.f : ac0) + b2v;
    ac1 = (ac1 == -FLT_MAX ? 0.f : ac1) + b2v;
    ac2 = (ac2 == -FLT_MAX ? 0.f : ac2) + b2v;
    ac3 = (ac3 == -FLT_MAX ? 0.f : ac3) + b2v;
#pragma unroll 8
    for (int i = 0; i < 32; ++i) {
        float w = wr2[i * 64 + lane];
        ac0 = fmaf(h1sh[wv][0][i], w, ac0);
        ac1 = fmaf(h1sh[wv][1][i], w, ac1);
        ac2 = fmaf(h1sh[wv][2][i], w, ac2);
        ac3 = fmaf(h1sh[wv][3][i], w, ac3);
    }
    h2sh[wv][0][lane] = elu_f(ac0);
    h2sh[wv][1][lane] = elu_f(ac1);
    h2sh[wv][2][lane] = elu_f(ac2);
    h2sh[wv][3][lane] = elu_f(ac3);

    float fb1 = fc1b[lane], fb2 = fc1b[64 + lane];
    float p0 = fb1, p1 = fb1, p2 = fb1, p3 = fb1;
    float q0 = fb2, q1 = fb2, q2 = fb2, q3 = fb2;
#pragma unroll 2
    for (int k4 = 0; k4 < 16; ++k4) {
        int k = k4 * 4;
        float wA0 = fc1w[(k + 0) * 128 + lane];
        float wB0 = fc1w[(k + 0) * 128 + 64 + lane];
        float wA1 = fc1w[(k + 1) * 128 + lane];
        float wB1 = fc1w[(k + 1) * 128 + 64 + lane];
        float wA2 = fc1w[(k + 2) * 128 + lane];
        float wB2 = fc1w[(k + 2) * 128 + 64 + lane];
        float wA3 = fc1w[(k + 3) * 128 + lane];
        float wB3 = fc1w[(k + 3) * 128 + 64 + lane];
        float4 g0 = ((const float4*)h2sh[wv][0])[k4];
        float4 g1 = ((const float4*)h2sh[wv][1])[k4];
        float4 g2 = ((const float4*)h2sh[wv][2])[k4];
        float4 g3 = ((const float4*)h2sh[wv][3])[k4];
        p0 = fmaf(g0.x, wA0, p0); p0 = fmaf(g0.y, wA1, p0);
        p0 = fmaf(g0.z, wA2, p0); p0 = fmaf(g0.w, wA3, p0);
        q0 = fmaf(g0.x, wB0, q0); q0 = fmaf(g0.y, wB1, q0);
        q0 = fmaf(g0.z, wB2, q0); q0 = fmaf(g0.w, wB3, q0);
        p1 = fmaf(g1.x, wA0, p1); p1 = fmaf(g1.y, wA1, p1);
        p1 = fmaf(g1.z, wA2, p1); p1 = fmaf(g1.w, wA3, p1);
        q1 = fmaf(g1.x, wB0, q1); q1 = fmaf(g1.y, wB1, q1);
        q1 = fmaf(g1.z, wB2, q1); q1 = fmaf(g1.w, wB3, q1);
        p2 = fmaf(g2.x, wA0, p2); p2 = fmaf(g2.y, wA1, p2);
        p2 = fmaf(g2.z, wA2, p2); p2 = fmaf(g2.w, wA3, p2);
        q2 = fmaf(g2.x, wB0, q2); q2 = fmaf(g2.y, wB1, q2);
        q2 = fmaf(g2.z, wB2, q2); q2 = fmaf(g2.w, wB3, q2);
        p3 = fmaf(g3.x, wA0, p3); p3 = fmaf(g3.y, wA1, p3);
        p3 = fmaf(g3.z, wA2, p3); p3 = fmaf(g3.w, wA3, p3);
        q3 = fmaf(g3.x, wB0, q3); q3 = fmaf(g3.y, wB1, q3);
        q3 = fmaf(g3.z, wB2, q3); q3 = fmaf(g3.w, wB3, q3);
    }
    h3sh[wv][0][lane] = elu_f(p0); h3sh[wv][0][64 + lane] = elu_f(q0);
    h3sh[wv][1][lane] = elu_f(p1); h3sh[wv][1][64 + lane] = elu_f(q1);
    h3sh[wv][2][lane] = elu_f(p2); h3sh[wv][2][64 + lane] = elu_f(q2);
    h3sh[wv][3][lane] = elu_f(p3); h3sh[wv][3][64 + lane] = elu_f(q3);

    {
        int n = lane >> 4, j = lane & 15;
        bool act = j < 10;
        int jc = act ? j : 0;
        float a = fc2b[jc];
        const float4* h3v = (const float4*)h3sh[wv][n];
        const float4* wv4 = (const float4*)wTsh[jc];
#pragma unroll
        for (int q = 0; q < 32; ++q) {
            float4 h = h3v[q];
            float4 w = wv4[q];
            a = fmaf(h.x, w.x, a);
            a = fmaf(h.y, w.y, a);
            a = fmaf(h.z, w.z, a);
            a = fmaf(h.w, w.w, a);
        }
        float lm = act ? a : -FLT_MAX;
        lm = fmaxf(lm, __shfl_xor(lm, 1, 16));
        lm = fmaxf(lm, __shfl_xor(lm, 2, 16));
        lm = fmaxf(lm, __shfl_xor(lm, 4, 16));
        lm = fmaxf(lm, __shfl_xor(lm, 8, 16));
        float ls = act ? expf(a - lm) : 0.f;
        ls += __shfl_xor(ls, 1, 16);
        ls += __shfl_xor(ls, 2, 16);
        ls += __shfl_xor(ls, 4, 16);
        ls += __shfl_xor(ls, 8, 16);
        if (act) out[(size_t)(nb + n) * 10 + j] = a - lm - logf(ls);
    }
}

extern "C" void kernel_launch(void* const* d_in, const int* in_sizes, int n_in,
                              void* d_out, int out_size, void* d_ws, size_t ws_size,
                              hipStream_t stream) {
    const float* x     = (const float*)d_in[0];
    const int*   eidx  = (const int*)d_in[1];
    const float* ea    = (const float*)d_in[2];
    const float* w1a   = (const float*)d_in[3];
    const float* b1a   = (const float*)d_in[4];
    const float* w1b   = (const float*)d_in[5];
    const float* b1b   = (const float*)d_in[6];
    const float* wr1   = (const float*)d_in[7];
    const float* bias1 = (const float*)d_in[8];
    const float* w2a   = (const float*)d_in[9];
    const float* b2a   = (const float*)d_in[10];
    const float* w2b   = (const float*)d_in[11];
    const float* b2b   = (const float*)d_in[12];
    const float* wr2   = (const float*)d_in[13];
    const float* bias2 = (const float*)d_in[14];
    const float* fc1w  = (const float*)d_in[15];
    const float* fc1b  = (const float*)d_in[16];
    const float* fc2w  = (const float*)d_in[17];
    const float* fc2b  = (const float*)d_in[18];

    const int N = in_sizes[0] / 16;   // 20000
    const int E = in_sizes[2];        // 100000
    const int* src = eidx;
    const int* tgt = eidx + E;

    const int cap1 = ((E + 26 * (CH1 - 1)) + CH1 - 1) / CH1 * CH1;
    const int cap2 = ((E + 26 * (CH2 - 1)) + CH2 - 1) / CH2 * CH2;

    float* ws = (float*)d_ws;
    size_t off = 0;
    int*   hist = (int*)(ws + off);   off += 64;   // hist+cur contiguous: 512B memset
    int*   cur  = (int*)(ws + off);   off += 64;
    int*   segp = (int*)(ws + off);   off += E;
    int*   ord1 = (int*)(ws + off);   off += cap1; // ord1/ord2 contiguous
    int*   ord2 = (int*)(ws + off);   off += cap2;
    float* U1   = ws + off;           off += 26 * 512;
    float* V1   = ws + off;           off += 26 * 512;
    float* U2   = ws + off;           off += 26 * 2048;
    float* V2   = ws + off;           off += 26 * 2048;
    float* AGG1 = ws + off;           off += (size_t)N * 32;  // AGG1/AGG2 contiguous
    float* AGG2 = ws + off;           off += (size_t)N * 64;
    float* H1b  = ws + off;           off += (size_t)N * 32;

    const int nAssign = (E + 255) / 256;   // 391

    PrepParams pp;
    pp.ea = ea; pp.w1a = w1a; pp.b1a = b1a; pp.w1b = w1b; pp.b1b = b1b;
    pp.w2a = w2a; pp.b2a = b2a; pp.w2b = w2b; pp.b2b = b2b;
    pp.hist = hist; pp.segp = segp; pp.ord1 = ord1;
    pp.U1 = U1; pp.V1 = V1; pp.U2 = U2; pp.V2 = V2; pp.AGG1 = AGG1;
    pp.N = N; pp.E = E; pp.capSum = cap1 + cap2;

    // 0. hist + cur = 0 (512 B; graph-capturable)
    hipMemsetAsync(hist, 0, 512, stream);
    // 1. fused fill + build_uv + assign_hist
    prep_kernel<<<K1_FILL + K1_UV + nAssign, 256, 0, stream>>>(pp);
    // 2. scatter with in-block scan (scanpad folded in)
    scatter_scan_kernel<<<nAssign, 256, 0, stream>>>(segp, E, hist, cur, ord1, ord2);
    // 3. conv1 edges
    {
        int waves = cap1 / CH1;
        edge1_kernel<<<(waves + 3) / 4, 256, 0, stream>>>(x, src, tgt, ea, ord1, cap1, U1, V1, AGG1);
    }
    // 4. conv1 node update
    node1_kernel<<<(N * 32 + 255) / 256, 256, 0, stream>>>(x, AGG1, wr1, bias1, H1b, N);
    // 5. conv2 edges
    {
        int waves = cap2 / CH2;
        edge2_kernel<<<(waves + 3) / 4, 256, 0, stream>>>(H1b, src, tgt, ea, ord2, cap2, U2, V2, AGG2);
    }
    // 6. fused node2 + fc1 + fc2 + log_softmax
    tail_kernel<<<N / 16, 256, 0, stream>>>(H1b, AGG2, wr2, bias2, fc1w, fc1b, fc2w, fc2b, (float*)d_out);
}

// Round 10
// 196.068 us; speedup vs baseline: 1.0940x; 1.0940x over previous
//
#include <hip/hip_runtime.h>
#include <float.h>
#include <math.h>

// NNConv net: 2x edge-conditioned conv (scalar edge attr) + 2 FC + log_softmax.
// W_e = a_e*U_s + V_s over <=26 breakpoint segments of the scalar edge attr.
// Edges bucketed by segment (chunk-aligned so a wave chunk is single-segment).
// R7: tail 4-nodes/wave loop-order reuse -> 198 us. R8/R9: cooperative fusion
// FALSIFIED (997 us). R10: float4 inner-loop x loads -> edge2 spill (94 us).
// R11: prep fusion + scatter-with-folded-scan + memset + R7 edge bodies ->
//      189.7 us (best).
// R12: LDS x-row staging in edges -> edge2 spill AGAIN (VGPR=64, WRITE 87 MB,
//      75 us). LESSON (3rd hit): any added VGPR-touching complexity in edge2's
//      prologue flips the allocator to a 64-VGPR target and Ur/Vr (64 regs)
//      spill. The R7/R11 body sits just under the cliff - do not perturb it.
// R13: exact R11 edge bodies; single parameter change CH2 16->32: halves the
//      per-wave-amortized U/V refetch (16 KB/wave over 2x edges), zero change
//      to the register structure.

#define NCONST 25
#define CH1 32   // edges per wave chunk, conv1
#define CH2 32   // edges per wave chunk, conv2 (R13: was 16; halves U/V refetch)
#define PACK_MASK 0x1FFFF  // edge id < 2^17 (E = 100000)
#define TNB 4    // nodes per wave in tail
#define K1_FILL 64
#define K1_UV   260

__device__ __forceinline__ void atomicMaxFloat(float* addr, float val) {
    if (val >= 0.f) atomicMax((int*)addr, __float_as_int(val));
    else            atomicMin((unsigned int*)addr, __float_as_uint(val));
}
__device__ __forceinline__ float readlane_f(float v, int l) {
    return __int_as_float(__builtin_amdgcn_readlane(__float_as_int(v), l));
}
__device__ __forceinline__ float elu_f(float a) {
    return a > 0.f ? a : expm1f(a);
}

struct PrepParams {
    const float *ea;
    const float *w1a, *b1a, *w1b, *b1b;
    const float *w2a, *b2a, *w2b, *b2b;
    int *hist, *segp, *ord1;               // ord1/ord2 contiguous; fill covers both
    float *U1, *V1, *U2, *V2, *AGG1;       // AGG1/AGG2 contiguous
    int N, E, capSum;
};

// ===== K1: fused {fill aggs/ords, build_uv, assign_hist}. Block role by
// blockIdx range; sections mutually independent (hist pre-zeroed by memset).
__global__ void prep_kernel(PrepParams p) {
    __shared__ float t1[NCONST], t2[NCONST];
    __shared__ int lh[64];
    __shared__ float swa[NCONST], sba[NCONST], stt[NCONST];
    __shared__ int srk[NCONST];
    __shared__ unsigned msk_sh;
    const int bid = blockIdx.x, tid = threadIdx.x;

    if (bid < K1_FILL) {
        int nAgg = p.N * 96, total = nAgg + p.capSum;
        for (int i = bid * 256 + tid; i < total; i += K1_FILL * 256) {
            if (i < nAgg) p.AGG1[i] = -FLT_MAX;
            else p.ord1[i - nAgg] = -1;
        }
    } else if (bid < K1_FILL + K1_UV) {
        int v = bid - K1_FILL;
        int seg = v / 10;
        int bx  = v % 10;
        int conv = (bx < 2) ? 0 : 1;
        const float* wa = conv ? p.w2a : p.w1a;
        const float* ba = conv ? p.b2a : p.b1a;
        if (tid < NCONST) {
            float w = wa[tid], b = ba[tid];
            swa[tid] = w; sba[tid] = b;
            stt[tid] = (w != 0.f) ? (-b / w) : INFINITY;
        }
        __syncthreads();
        if (tid < NCONST) {
            int rk = 0;
            for (int l = 0; l < NCONST; ++l) rk += (stt[l] < stt[tid]) ? 1 : 0;
            srk[tid] = rk;
        }
        __syncthreads();
        if (tid == 0) {
            unsigned m = 0;
            for (int k = 0; k < NCONST; ++k) {
                float w = swa[k];
                bool act = (w > 0.f) ? (seg > srk[k])
                         : (w < 0.f) ? (seg <= srk[k])
                                     : (sba[k] > 0.f);
                if (act) m |= (1u << k);
            }
            msk_sh = m;
        }
        __syncthreads();
        unsigned msk = msk_sh;
        if (conv == 0) {
            int idx = bx * 256 + tid;           // < 512
            float u = 0.f, vv = 0.f;
            for (int k = 0; k < NCONST; ++k)
                if (msk & (1u << k)) { float w = p.w1b[k * 512 + idx]; u = fmaf(swa[k], w, u); vv = fmaf(sba[k], w, vv); }
            vv += p.b1b[idx];
            p.U1[seg * 512 + idx] = u; p.V1[seg * 512 + idx] = vv;
        } else {
            int idx = (bx - 2) * 256 + tid;     // < 2048
            float u = 0.f, vv = 0.f;
            for (int k = 0; k < NCONST; ++k)
                if (msk & (1u << k)) { float w = p.w2b[k * 2048 + idx]; u = fmaf(swa[k], w, u); vv = fmaf(sba[k], w, vv); }
            vv += p.b2b[idx];
            p.U2[seg * 2048 + idx] = u; p.V2[seg * 2048 + idx] = vv;
        }
    } else {
        if (tid < NCONST) {
            float w = p.w1a[tid]; t1[tid] = (w != 0.f) ? (-p.b1a[tid] / w) : INFINITY;
            float v = p.w2a[tid]; t2[tid] = (v != 0.f) ? (-p.b2a[tid] / v) : INFINITY;
        }
        if (tid < 64) lh[tid] = 0;
        __syncthreads();
        int e = (bid - K1_FILL - K1_UV) * 256 + tid;
        if (e < p.E) {
            float a = p.ea[e];
            int j1 = 0, j2 = 0;
            for (int k = 0; k < NCONST; ++k) { j1 += (t1[k] < a); j2 += (t2[k] < a); }
            p.segp[e] = j1 | (j2 << 8);
            atomicAdd(&lh[j1], 1); atomicAdd(&lh[32 + j2], 1);
        }
        __syncthreads();
        if (tid < 64 && lh[tid]) atomicAdd(&p.hist[tid], lh[tid]);
    }
}

// ===== K2: scatter with in-block scan (scanpad folded in).
__global__ void scatter_scan_kernel(const int* __restrict__ segpack, int E,
                                    const int* __restrict__ hist, int* __restrict__ cur,
                                    int* __restrict__ order1, int* __restrict__ order2) {
    __shared__ int h[64], sbase[64], lh[64], lb[64];
    int tid = threadIdx.x;
    if (tid < 64) h[tid] = hist[tid];
    __syncthreads();
    if (tid == 0) {
        int off = 0;
        for (int j = 0; j < 26; ++j) { sbase[j] = off; off += ((h[j] + CH1 - 1) / CH1) * CH1; }
    } else if (tid == 1) {
        int off = 0;
        for (int j = 0; j < 26; ++j) { sbase[32 + j] = off; off += ((h[32 + j] + CH2 - 1) / CH2) * CH2; }
    }
    if (tid < 64) lh[tid] = 0;
    __syncthreads();
    int e = blockIdx.x * 256 + tid;
    bool valid = e < E;
    int j1 = 0, j2 = 0, r1 = 0, r2 = 0;
    if (valid) {
        int pk = segpack[e]; j1 = pk & 0xFF; j2 = pk >> 8;
        r1 = atomicAdd(&lh[j1], 1); r2 = atomicAdd(&lh[32 + j2], 1);
    }
    __syncthreads();
    if (tid < 64 && lh[tid]) lb[tid] = sbase[tid] + atomicAdd(&cur[tid], lh[tid]);
    __syncthreads();
    if (valid) {
        order1[lb[j1] + r1] = (j1 << 17) | e;
        order2[lb[32 + j2] + r2] = (j2 << 17) | e;
    }
}

// ===== edge1: IC=16, OC=32, half-wave per edge (2 edges/iter). R7/R11 body:
// wave-uniform scalar x loads (s_load path), per-lane U/V register cache.
__global__ void edge1_kernel(const float* __restrict__ xin, const int* __restrict__ src,
                             const int* __restrict__ tgt, const float* __restrict__ ea,
                             const int* __restrict__ order, int cap,
                             const float* __restrict__ U, const float* __restrict__ V,
                             float* __restrict__ agg) {
    int wid = (blockIdx.x * blockDim.x + threadIdx.x) >> 6;
    int lane = threadIdx.x & 63;
    int base = wid * CH1;
    if (base >= cap) return;
    int pk = order[base + (lane & (CH1 - 1))];
    int p0 = __builtin_amdgcn_readfirstlane(pk);
    if (p0 < 0) return;                        // whole-pad chunk past used region
    int seg = p0 >> 17;
    int ev = (pk < 0) ? 0 : (pk & PACK_MASK);
    int sv = src[ev], tv = tgt[ev];
    float av = ea[ev];
    int half = lane >> 5, c = lane & 31;
    float Ur[16], Vr[16];
    {
        const float* Us = U + seg * 512 + c;
        const float* Vs = V + seg * 512 + c;
#pragma unroll
        for (int i = 0; i < 16; ++i) { Ur[i] = Us[i * 32]; Vr[i] = Vs[i * 32]; }
    }
#pragma unroll
    for (int t = 0; t < CH1; t += 2) {
        int pA = __builtin_amdgcn_readlane(pk, t);
        int pB = __builtin_amdgcn_readlane(pk, t + 1);
        int sA = __builtin_amdgcn_readlane(sv, t);
        int sB = __builtin_amdgcn_readlane(sv, t + 1);
        int tA = __builtin_amdgcn_readlane(tv, t);
        int tB = __builtin_amdgcn_readlane(tv, t + 1);
        float aA = readlane_f(av, t);
        float aB = readlane_f(av, t + 1);
        const float* xA = xin + sA * 16;
        const float* xB = xin + sB * 16;
        float ah = half ? aB : aA;
        int   th = half ? tB : tA;
        int   ph = half ? pB : pA;
        float acc = 0.f;
#pragma unroll
        for (int i = 0; i < 16; ++i) {
            float xi = half ? xB[i] : xA[i];
            acc = fmaf(xi, fmaf(ah, Ur[i], Vr[i]), acc);
        }
        if (ph >= 0) atomicMaxFloat(&agg[th * 32 + c], acc);
    }
}

// ===== edge2: IC=32, OC=64, lane = out channel, A/B edge pair. R7/R11 body;
// only CH2 changed (32 edges/chunk -> U/V register load amortized 2x).
__global__ void edge2_kernel(const float* __restrict__ xin, const int* __restrict__ src,
                             const int* __restrict__ tgt, const float* __restrict__ ea,
                             const int* __restrict__ order, int cap,
                             const float* __restrict__ U, const float* __restrict__ V,
                             float* __restrict__ agg) {
    int wid = (blockIdx.x * blockDim.x + threadIdx.x) >> 6;
    int lane = threadIdx.x & 63;
    int base = wid * CH2;
    if (base >= cap) return;
    int pk = order[base + (lane & (CH2 - 1))];
    int p0 = __builtin_amdgcn_readfirstlane(pk);
    if (p0 < 0) return;
    int seg = p0 >> 17;
    int ev = (pk < 0) ? 0 : (pk & PACK_MASK);
    int sv = src[ev], tv = tgt[ev];
    float av = ea[ev];
    float Ur[32], Vr[32];
    {
        const float* Us = U + seg * 2048 + lane;
        const float* Vs = V + seg * 2048 + lane;
#pragma unroll
        for (int i = 0; i < 32; ++i) { Ur[i] = Us[i * 64]; Vr[i] = Vs[i * 64]; }
    }
#pragma unroll
    for (int t = 0; t < CH2; t += 2) {
        int pA = __builtin_amdgcn_readlane(pk, t);
        int pB = __builtin_amdgcn_readlane(pk, t + 1);
        int sA = __builtin_amdgcn_readlane(sv, t);
        int sB = __builtin_amdgcn_readlane(sv, t + 1);
        int tA = __builtin_amdgcn_readlane(tv, t);
        int tB = __builtin_amdgcn_readlane(tv, t + 1);
        float aA = readlane_f(av, t);
        float aB = readlane_f(av, t + 1);
        const float* xA = xin + sA * 32;
        const float* xB = xin + sB * 32;
        float accA = 0.f, accB = 0.f;
#pragma unroll
        for (int i = 0; i < 32; ++i) {
            accA = fmaf(xA[i], fmaf(aA, Ur[i], Vr[i]), accA);
            accB = fmaf(xB[i], fmaf(aB, Ur[i], Vr[i]), accB);
        }
        if (pA >= 0) atomicMaxFloat(&agg[tA * 64 + lane], accA);
        if (pB >= 0) atomicMaxFloat(&agg[tB * 64 + lane], accB);
    }
}

// ===== node1: out = elu( fixup(agg) + x @ wr1 + bias1 ). R7 body.
__global__ void node1_kernel(const float* __restrict__ xin, const float* __restrict__ agg,
                             const float* __restrict__ wroot, const float* __restrict__ bias,
                             float* __restrict__ out, int N) {
    int idx = blockIdx.x * blockDim.x + threadIdx.x;
    if (idx >= N * 32) return;
    int n = idx >> 5, c = idx & 31;
    float v = agg[idx];
    if (v == -FLT_MAX) v = 0.f;
    float acc = v + bias[c];
#pragma unroll
    for (int i = 0; i < 16; ++i) acc = fmaf(xin[n * 16 + i], wroot[i * 32 + c], acc);
    out[idx] = acc > 0.f ? acc : expm1f(acc);
}

// ===== tail: node2 + fc1 + fc2 + log_softmax. R7 body: 4 nodes/wave, zero
// local arrays (allocator pins 64-VGPR budget; register arrays spill).
__global__ void tail_kernel(const float* __restrict__ h1, const float* __restrict__ agg2,
                            const float* __restrict__ wr2, const float* __restrict__ bias2,
                            const float* __restrict__ fc1w, const float* __restrict__ fc1b,
                            const float* __restrict__ fc2w, const float* __restrict__ fc2b,
                            float* __restrict__ out) {
    __shared__ __align__(16) float h1sh[4][TNB][32];
    __shared__ __align__(16) float h2sh[4][TNB][64];
    __shared__ __align__(16) float h3sh[4][TNB][132];   // +4 pad
    __shared__ __align__(16) float wTsh[10][132];       // fc2w transposed
    int tid = threadIdx.x;
    int wv = tid >> 6, lane = tid & 63;

    for (int t = tid; t < 1280; t += 256) {
        int k = t / 10, j = t - k * 10;
        wTsh[j][k] = fc2w[t];
    }
    __syncthreads();   // only barrier; everything below is wave-local

    int nb = blockIdx.x * (4 * TNB) + wv * TNB;

    {
        const float2* hp = (const float2*)(h1 + (size_t)nb * 32);
        ((float2*)&h1sh[wv][0][0])[lane] = hp[lane];
    }

    float b2v = bias2[lane];
    float ac0 = agg2[(size_t)(nb + 0) * 64 + lane];
    float ac1 = agg2[(size_t)(nb + 1) * 64 + lane];
    float ac2 = agg2[(size_t)(nb + 2) * 64 + lane];
    float ac3 = agg2[(size_t)(nb + 3) * 64 + lane];
    ac0 = (ac0 == -FLT_MAX ? 0.f : ac0) + b2v;
    ac1 = (ac1 == -FLT_MAX ? 0.f : ac1) + b2v;
    ac2 = (ac2 == -FLT_MAX ? 0.f : ac2) + b2v;
    ac3 = (ac3 == -FLT_MAX ? 0.f : ac3) + b2v;
#pragma unroll 8
    for (int i = 0; i < 32; ++i) {
        float w = wr2[i * 64 + lane];
        ac0 = fmaf(h1sh[wv][0][i], w, ac0);
        ac1 = fmaf(h1sh[wv][1][i], w, ac1);
        ac2 = fmaf(h1sh[wv][2][i], w, ac2);
        ac3 = fmaf(h1sh[wv][3][i], w, ac3);
    }
    h2sh[wv][0][lane] = elu_f(ac0);
    h2sh[wv][1][lane] = elu_f(ac1);
    h2sh[wv][2][lane] = elu_f(ac2);
    h2sh[wv][3][lane] = elu_f(ac3);

    float fb1 = fc1b[lane], fb2 = fc1b[64 + lane];
    float p0 = fb1, p1 = fb1, p2 = fb1, p3 = fb1;
    float q0 = fb2, q1 = fb2, q2 = fb2, q3 = fb2;
#pragma unroll 2
    for (int k4 = 0; k4 < 16; ++k4) {
        int k = k4 * 4;
        float wA0 = fc1w[(k + 0) * 128 + lane];
        float wB0 = fc1w[(k + 0) * 128 + 64 + lane];
        float wA1 = fc1w[(k + 1) * 128 + lane];
        float wB1 = fc1w[(k + 1) * 128 + 64 + lane];
        float wA2 = fc1w[(k + 2) * 128 + lane];
        float wB2 = fc1w[(k + 2) * 128 + 64 + lane];
        float wA3 = fc1w[(k + 3) * 128 + lane];
        float wB3 = fc1w[(k + 3) * 128 + 64 + lane];
        float4 g0 = ((const float4*)h2sh[wv][0])[k4];
        float4 g1 = ((const float4*)h2sh[wv][1])[k4];
        float4 g2 = ((const float4*)h2sh[wv][2])[k4];
        float4 g3 = ((const float4*)h2sh[wv][3])[k4];
        p0 = fmaf(g0.x, wA0, p0); p0 = fmaf(g0.y, wA1, p0);
        p0 = fmaf(g0.z, wA2, p0); p0 = fmaf(g0.w, wA3, p0);
        q0 = fmaf(g0.x, wB0, q0); q0 = fmaf(g0.y, wB1, q0);
        q0 = fmaf(g0.z, wB2, q0); q0 = fmaf(g0.w, wB3, q0);
        p1 = fmaf(g1.x, wA0, p1); p1 = fmaf(g1.y, wA1, p1);
        p1 = fmaf(g1.z, wA2, p1); p1 = fmaf(g1.w, wA3, p1);
        q1 = fmaf(g1.x, wB0, q1); q1 = fmaf(g1.y, wB1, q1);
        q1 = fmaf(g1.z, wB2, q1); q1 = fmaf(g1.w, wB3, q1);
        p2 = fmaf(g2.x, wA0, p2); p2 = fmaf(g2.y, wA1, p2);
        p2 = fmaf(g2.z, wA2, p2); p2 = fmaf(g2.w, wA3, p2);
        q2 = fmaf(g2.x, wB0, q2); q2 = fmaf(g2.y, wB1, q2);
        q2 = fmaf(g2.z, wB2, q2); q2 = fmaf(g2.w, wB3, q2);
        p3 = fmaf(g3.x, wA0, p3); p3 = fmaf(g3.y, wA1, p3);
        p3 = fmaf(g3.z, wA2, p3); p3 = fmaf(g3.w, wA3, p3);
        q3 = fmaf(g3.x, wB0, q3); q3 = fmaf(g3.y, wB1, q3);
        q3 = fmaf(g3.z, wB2, q3); q3 = fmaf(g3.w, wB3, q3);
    }
    h3sh[wv][0][lane] = elu_f(p0); h3sh[wv][0][64 + lane] = elu_f(q0);
    h3sh[wv][1][lane] = elu_f(p1); h3sh[wv][1][64 + lane] = elu_f(q1);
    h3sh[wv][2][lane] = elu_f(p2); h3sh[wv][2][64 + lane] = elu_f(q2);
    h3sh[wv][3][lane] = elu_f(p3); h3sh[wv][3][64 + lane] = elu_f(q3);

    {
        int n = lane >> 4, j = lane & 15;
        bool act = j < 10;
        int jc = act ? j : 0;
        float a = fc2b[jc];
        const float4* h3v = (const float4*)h3sh[wv][n];
        const float4* wv4 = (const float4*)wTsh[jc];
#pragma unroll
        for (int q = 0; q < 32; ++q) {
            float4 h = h3v[q];
            float4 w = wv4[q];
            a = fmaf(h.x, w.x, a);
            a = fmaf(h.y, w.y, a);
            a = fmaf(h.z, w.z, a);
            a = fmaf(h.w, w.w, a);
        }
        float lm = act ? a : -FLT_MAX;
        lm = fmaxf(lm, __shfl_xor(lm, 1, 16));
        lm = fmaxf(lm, __shfl_xor(lm, 2, 16));
        lm = fmaxf(lm, __shfl_xor(lm, 4, 16));
        lm = fmaxf(lm, __shfl_xor(lm, 8, 16));
        float ls = act ? expf(a - lm) : 0.f;
        ls += __shfl_xor(ls, 1, 16);
        ls += __shfl_xor(ls, 2, 16);
        ls += __shfl_xor(ls, 4, 16);
        ls += __shfl_xor(ls, 8, 16);
        if (act) out[(size_t)(nb + n) * 10 + j] = a - lm - logf(ls);
    }
}

extern "C" void kernel_launch(void* const* d_in, const int* in_sizes, int n_in,
                              void* d_out, int out_size, void* d_ws, size_t ws_size,
                              hipStream_t stream) {
    const float* x     = (const float*)d_in[0];
    const int*   eidx  = (const int*)d_in[1];
    const float* ea    = (const float*)d_in[2];
    const float* w1a   = (const float*)d_in[3];
    const float* b1a   = (const float*)d_in[4];
    const float* w1b   = (const float*)d_in[5];
    const float* b1b   = (const float*)d_in[6];
    const float* wr1   = (const float*)d_in[7];
    const float* bias1 = (const float*)d_in[8];
    const float* w2a   = (const float*)d_in[9];
    const float* b2a   = (const float*)d_in[10];
    const float* w2b   = (const float*)d_in[11];
    const float* b2b   = (const float*)d_in[12];
    const float* wr2   = (const float*)d_in[13];
    const float* bias2 = (const float*)d_in[14];
    const float* fc1w  = (const float*)d_in[15];
    const float* fc1b  = (const float*)d_in[16];
    const float* fc2w  = (const float*)d_in[17];
    const float* fc2b  = (const float*)d_in[18];

    const int N = in_sizes[0] / 16;   // 20000
    const int E = in_sizes[2];        // 100000
    const int* src = eidx;
    const int* tgt = eidx + E;

    const int cap1 = ((E + 26 * (CH1 - 1)) + CH1 - 1) / CH1 * CH1;
    const int cap2 = ((E + 26 * (CH2 - 1)) + CH2 - 1) / CH2 * CH2;

    float* ws = (float*)d_ws;
    size_t off = 0;
    int*   hist = (int*)(ws + off);   off += 64;   // hist+cur contiguous: 512B memset
    int*   cur  = (int*)(ws + off);   off += 64;
    int*   segp = (int*)(ws + off);   off += E;
    int*   ord1 = (int*)(ws + off);   off += cap1; // ord1/ord2 contiguous
    int*   ord2 = (int*)(ws + off);   off += cap2;
    float* U1   = ws + off;           off += 26 * 512;
    float* V1   = ws + off;           off += 26 * 512;
    float* U2   = ws + off;           off += 26 * 2048;
    float* V2   = ws + off;           off += 26 * 2048;
    float* AGG1 = ws + off;           off += (size_t)N * 32;  // AGG1/AGG2 contiguous
    float* AGG2 = ws + off;           off += (size_t)N * 64;
    float* H1b  = ws + off;           off += (size_t)N * 32;

    const int nAssign = (E + 255) / 256;   // 391

    PrepParams pp;
    pp.ea = ea; pp.w1a = w1a; pp.b1a = b1a; pp.w1b = w1b; pp.b1b = b1b;
    pp.w2a = w2a; pp.b2a = b2a; pp.w2b = w2b; pp.b2b = b2b;
    pp.hist = hist; pp.segp = segp; pp.ord1 = ord1;
    pp.U1 = U1; pp.V1 = V1; pp.U2 = U2; pp.V2 = V2; pp.AGG1 = AGG1;
    pp.N = N; pp.E = E; pp.capSum = cap1 + cap2;

    // 0. hist + cur = 0 (512 B; graph-capturable)
    hipMemsetAsync(hist, 0, 512, stream);
    // 1. fused fill + build_uv + assign_hist
    prep_kernel<<<K1_FILL + K1_UV + nAssign, 256, 0, stream>>>(pp);
    // 2. scatter with in-block scan (scanpad folded in)
    scatter_scan_kernel<<<nAssign, 256, 0, stream>>>(segp, E, hist, cur, ord1, ord2);
    // 3. conv1 edges
    {
        int waves = cap1 / CH1;
        edge1_kernel<<<(waves + 3) / 4, 256, 0, stream>>>(x, src, tgt, ea, ord1, cap1, U1, V1, AGG1);
    }
    // 4. conv1 node update
    node1_kernel<<<(N * 32 + 255) / 256, 256, 0, stream>>>(x, AGG1, wr1, bias1, H1b, N);
    // 5. conv2 edges
    {
        int waves = cap2 / CH2;
        edge2_kernel<<<(waves + 3) / 4, 256, 0, stream>>>(H1b, src, tgt, ea, ord2, cap2, U2, V2, AGG2);
    }
    // 6. fused node2 + fc1 + fc2 + log_softmax
    tail_kernel<<<N / 16, 256, 0, stream>>>(H1b, AGG2, wr2, bias2, fc1w, fc1b, fc2w, fc2b, (float*)d_out);
}

// Round 11
// 192.181 us; speedup vs baseline: 1.1162x; 1.0202x over previous
//
#include <hip/hip_runtime.h>
#include <float.h>
#include <math.h>

// NNConv net: 2x edge-conditioned conv (scalar edge attr) + 2 FC + log_softmax.
// W_e = a_e*U_s + V_s over <=26 breakpoint segments of the scalar edge attr.
// Edges bucketed by segment (chunk-aligned so a wave chunk is single-segment).
// R7: tail 4-nodes/wave loop-order reuse -> 198 us. R8/R9: cooperative fusion
// FALSIFIED (997 us, grid.sync+fences serialize through 8 XCD TCCs).
// R10: float4 inner-loop x loads -> edge2 spill (94 us).
// R11: prep fusion {fill,build_uv,assign_hist} + scatter-with-folded-scan +
//      512B memset + R7 edge bodies -> 189.7 us (BEST).
// R12: LDS x-row staging -> edge2 spill again (VGPR=64, WRITE 87 MB).
// R13: CH2 16->32 halved U/V refetch (FETCH 22.5->10.3 MB, as predicted) BUT
//      the 2x-longer unroll flipped the allocator to VGPR=48 -> Ur/Vr scratch
//      (WRITE 50 MB) -> net 196 us. 4th allocator-cliff hit on edge bodies.
// R14: exact R11 restore. The R7/R11 edge body is the allocator sweet spot;
//      every perturbation (R10/R12/R13) demoted the 64-float U/V register
//      cache to scratch. Remaining cost = 6 serialized launches + latency-
//      bound edge kernels; no dispatch above the harness's 42 us re-poison.

#define NCONST 25
#define CH1 32   // edges per wave chunk, conv1
#define CH2 16   // edges per wave chunk, conv2 (R13's 32 spilled; keep 16)
#define PACK_MASK 0x1FFFF  // edge id < 2^17 (E = 100000)
#define TNB 4    // nodes per wave in tail
#define K1_FILL 64
#define K1_UV   260

__device__ __forceinline__ void atomicMaxFloat(float* addr, float val) {
    if (val >= 0.f) atomicMax((int*)addr, __float_as_int(val));
    else            atomicMin((unsigned int*)addr, __float_as_uint(val));
}
__device__ __forceinline__ float readlane_f(float v, int l) {
    return __int_as_float(__builtin_amdgcn_readlane(__float_as_int(v), l));
}
__device__ __forceinline__ float elu_f(float a) {
    return a > 0.f ? a : expm1f(a);
}

struct PrepParams {
    const float *ea;
    const float *w1a, *b1a, *w1b, *b1b;
    const float *w2a, *b2a, *w2b, *b2b;
    int *hist, *segp, *ord1;               // ord1/ord2 contiguous; fill covers both
    float *U1, *V1, *U2, *V2, *AGG1;       // AGG1/AGG2 contiguous
    int N, E, capSum;
};

// ===== K1: fused {fill aggs/ords, build_uv, assign_hist}. Block role by
// blockIdx range; sections mutually independent (hist pre-zeroed by memset).
__global__ void prep_kernel(PrepParams p) {
    __shared__ float t1[NCONST], t2[NCONST];
    __shared__ int lh[64];
    __shared__ float swa[NCONST], sba[NCONST], stt[NCONST];
    __shared__ int srk[NCONST];
    __shared__ unsigned msk_sh;
    const int bid = blockIdx.x, tid = threadIdx.x;

    if (bid < K1_FILL) {
        int nAgg = p.N * 96, total = nAgg + p.capSum;
        for (int i = bid * 256 + tid; i < total; i += K1_FILL * 256) {
            if (i < nAgg) p.AGG1[i] = -FLT_MAX;
            else p.ord1[i - nAgg] = -1;
        }
    } else if (bid < K1_FILL + K1_UV) {
        int v = bid - K1_FILL;
        int seg = v / 10;
        int bx  = v % 10;
        int conv = (bx < 2) ? 0 : 1;
        const float* wa = conv ? p.w2a : p.w1a;
        const float* ba = conv ? p.b2a : p.b1a;
        if (tid < NCONST) {
            float w = wa[tid], b = ba[tid];
            swa[tid] = w; sba[tid] = b;
            stt[tid] = (w != 0.f) ? (-b / w) : INFINITY;
        }
        __syncthreads();
        if (tid < NCONST) {
            int rk = 0;
            for (int l = 0; l < NCONST; ++l) rk += (stt[l] < stt[tid]) ? 1 : 0;
            srk[tid] = rk;
        }
        __syncthreads();
        if (tid == 0) {
            unsigned m = 0;
            for (int k = 0; k < NCONST; ++k) {
                float w = swa[k];
                bool act = (w > 0.f) ? (seg > srk[k])
                         : (w < 0.f) ? (seg <= srk[k])
                                     : (sba[k] > 0.f);
                if (act) m |= (1u << k);
            }
            msk_sh = m;
        }
        __syncthreads();
        unsigned msk = msk_sh;
        if (conv == 0) {
            int idx = bx * 256 + tid;           // < 512
            float u = 0.f, vv = 0.f;
            for (int k = 0; k < NCONST; ++k)
                if (msk & (1u << k)) { float w = p.w1b[k * 512 + idx]; u = fmaf(swa[k], w, u); vv = fmaf(sba[k], w, vv); }
            vv += p.b1b[idx];
            p.U1[seg * 512 + idx] = u; p.V1[seg * 512 + idx] = vv;
        } else {
            int idx = (bx - 2) * 256 + tid;     // < 2048
            float u = 0.f, vv = 0.f;
            for (int k = 0; k < NCONST; ++k)
                if (msk & (1u << k)) { float w = p.w2b[k * 2048 + idx]; u = fmaf(swa[k], w, u); vv = fmaf(sba[k], w, vv); }
            vv += p.b2b[idx];
            p.U2[seg * 2048 + idx] = u; p.V2[seg * 2048 + idx] = vv;
        }
    } else {
        if (tid < NCONST) {
            float w = p.w1a[tid]; t1[tid] = (w != 0.f) ? (-p.b1a[tid] / w) : INFINITY;
            float v = p.w2a[tid]; t2[tid] = (v != 0.f) ? (-p.b2a[tid] / v) : INFINITY;
        }
        if (tid < 64) lh[tid] = 0;
        __syncthreads();
        int e = (bid - K1_FILL - K1_UV) * 256 + tid;
        if (e < p.E) {
            float a = p.ea[e];
            int j1 = 0, j2 = 0;
            for (int k = 0; k < NCONST; ++k) { j1 += (t1[k] < a); j2 += (t2[k] < a); }
            p.segp[e] = j1 | (j2 << 8);
            atomicAdd(&lh[j1], 1); atomicAdd(&lh[32 + j2], 1);
        }
        __syncthreads();
        if (tid < 64 && lh[tid]) atomicAdd(&p.hist[tid], lh[tid]);
    }
}

// ===== K2: scatter with in-block scan (scanpad folded in).
__global__ void scatter_scan_kernel(const int* __restrict__ segpack, int E,
                                    const int* __restrict__ hist, int* __restrict__ cur,
                                    int* __restrict__ order1, int* __restrict__ order2) {
    __shared__ int h[64], sbase[64], lh[64], lb[64];
    int tid = threadIdx.x;
    if (tid < 64) h[tid] = hist[tid];
    __syncthreads();
    if (tid == 0) {
        int off = 0;
        for (int j = 0; j < 26; ++j) { sbase[j] = off; off += ((h[j] + CH1 - 1) / CH1) * CH1; }
    } else if (tid == 1) {
        int off = 0;
        for (int j = 0; j < 26; ++j) { sbase[32 + j] = off; off += ((h[32 + j] + CH2 - 1) / CH2) * CH2; }
    }
    if (tid < 64) lh[tid] = 0;
    __syncthreads();
    int e = blockIdx.x * 256 + tid;
    bool valid = e < E;
    int j1 = 0, j2 = 0, r1 = 0, r2 = 0;
    if (valid) {
        int pk = segpack[e]; j1 = pk & 0xFF; j2 = pk >> 8;
        r1 = atomicAdd(&lh[j1], 1); r2 = atomicAdd(&lh[32 + j2], 1);
    }
    __syncthreads();
    if (tid < 64 && lh[tid]) lb[tid] = sbase[tid] + atomicAdd(&cur[tid], lh[tid]);
    __syncthreads();
    if (valid) {
        order1[lb[j1] + r1] = (j1 << 17) | e;
        order2[lb[32 + j2] + r2] = (j2 << 17) | e;
    }
}

// ===== edge1: IC=16, OC=32, half-wave per edge (2 edges/iter). R7/R11 body:
// wave-uniform scalar x loads (s_load path), per-lane U/V register cache.
// DO NOT PERTURB: R10/R12/R13 all tipped Ur/Vr into scratch.
__global__ void edge1_kernel(const float* __restrict__ xin, const int* __restrict__ src,
                             const int* __restrict__ tgt, const float* __restrict__ ea,
                             const int* __restrict__ order, int cap,
                             const float* __restrict__ U, const float* __restrict__ V,
                             float* __restrict__ agg) {
    int wid = (blockIdx.x * blockDim.x + threadIdx.x) >> 6;
    int lane = threadIdx.x & 63;
    int base = wid * CH1;
    if (base >= cap) return;
    int pk = order[base + (lane & (CH1 - 1))];
    int p0 = __builtin_amdgcn_readfirstlane(pk);
    if (p0 < 0) return;                        // whole-pad chunk past used region
    int seg = p0 >> 17;
    int ev = (pk < 0) ? 0 : (pk & PACK_MASK);
    int sv = src[ev], tv = tgt[ev];
    float av = ea[ev];
    int half = lane >> 5, c = lane & 31;
    float Ur[16], Vr[16];
    {
        const float* Us = U + seg * 512 + c;
        const float* Vs = V + seg * 512 + c;
#pragma unroll
        for (int i = 0; i < 16; ++i) { Ur[i] = Us[i * 32]; Vr[i] = Vs[i * 32]; }
    }
#pragma unroll
    for (int t = 0; t < CH1; t += 2) {
        int pA = __builtin_amdgcn_readlane(pk, t);
        int pB = __builtin_amdgcn_readlane(pk, t + 1);
        int sA = __builtin_amdgcn_readlane(sv, t);
        int sB = __builtin_amdgcn_readlane(sv, t + 1);
        int tA = __builtin_amdgcn_readlane(tv, t);
        int tB = __builtin_amdgcn_readlane(tv, t + 1);
        float aA = readlane_f(av, t);
        float aB = readlane_f(av, t + 1);
        const float* xA = xin + sA * 16;
        const float* xB = xin + sB * 16;
        float ah = half ? aB : aA;
        int   th = half ? tB : tA;
        int   ph = half ? pB : pA;
        float acc = 0.f;
#pragma unroll
        for (int i = 0; i < 16; ++i) {
            float xi = half ? xB[i] : xA[i];
            acc = fmaf(xi, fmaf(ah, Ur[i], Vr[i]), acc);
        }
        if (ph >= 0) atomicMaxFloat(&agg[th * 32 + c], acc);
    }
}

// ===== edge2: IC=32, OC=64, lane = out channel, A/B edge pair. R7/R11 body.
// DO NOT PERTURB (allocator cliff).
__global__ void edge2_kernel(const float* __restrict__ xin, const int* __restrict__ src,
                             const int* __restrict__ tgt, const float* __restrict__ ea,
                             const int* __restrict__ order, int cap,
                             const float* __restrict__ U, const float* __restrict__ V,
                             float* __restrict__ agg) {
    int wid = (blockIdx.x * blockDim.x + threadIdx.x) >> 6;
    int lane = threadIdx.x & 63;
    int base = wid * CH2;
    if (base >= cap) return;
    int pk = order[base + (lane & (CH2 - 1))];
    int p0 = __builtin_amdgcn_readfirstlane(pk);
    if (p0 < 0) return;
    int seg = p0 >> 17;
    int ev = (pk < 0) ? 0 : (pk & PACK_MASK);
    int sv = src[ev], tv = tgt[ev];
    float av = ea[ev];
    float Ur[32], Vr[32];
    {
        const float* Us = U + seg * 2048 + lane;
        const float* Vs = V + seg * 2048 + lane;
#pragma unroll
        for (int i = 0; i < 32; ++i) { Ur[i] = Us[i * 64]; Vr[i] = Vs[i * 64]; }
    }
#pragma unroll
    for (int t = 0; t < CH2; t += 2) {
        int pA = __builtin_amdgcn_readlane(pk, t);
        int pB = __builtin_amdgcn_readlane(pk, t + 1);
        int sA = __builtin_amdgcn_readlane(sv, t);
        int sB = __builtin_amdgcn_readlane(sv, t + 1);
        int tA = __builtin_amdgcn_readlane(tv, t);
        int tB = __builtin_amdgcn_readlane(tv, t + 1);
        float aA = readlane_f(av, t);
        float aB = readlane_f(av, t + 1);
        const float* xA = xin + sA * 32;
        const float* xB = xin + sB * 32;
        float accA = 0.f, accB = 0.f;
#pragma unroll
        for (int i = 0; i < 32; ++i) {
            accA = fmaf(xA[i], fmaf(aA, Ur[i], Vr[i]), accA);
            accB = fmaf(xB[i], fmaf(aB, Ur[i], Vr[i]), accB);
        }
        if (pA >= 0) atomicMaxFloat(&agg[tA * 64 + lane], accA);
        if (pB >= 0) atomicMaxFloat(&agg[tB * 64 + lane], accB);
    }
}

// ===== node1: out = elu( fixup(agg) + x @ wr1 + bias1 ). R7 body.
__global__ void node1_kernel(const float* __restrict__ xin, const float* __restrict__ agg,
                             const float* __restrict__ wroot, const float* __restrict__ bias,
                             float* __restrict__ out, int N) {
    int idx = blockIdx.x * blockDim.x + threadIdx.x;
    if (idx >= N * 32) return;
    int n = idx >> 5, c = idx & 31;
    float v = agg[idx];
    if (v == -FLT_MAX) v = 0.f;
    float acc = v + bias[c];
#pragma unroll
    for (int i = 0; i < 16; ++i) acc = fmaf(xin[n * 16 + i], wroot[i * 32 + c], acc);
    out[idx] = acc > 0.f ? acc : expm1f(acc);
}

// ===== tail: node2 + fc1 + fc2 + log_softmax. R7 body: 4 nodes/wave, zero
// local arrays (allocator pins 64-VGPR budget; register arrays spill).
__global__ void tail_kernel(const float* __restrict__ h1, const float* __restrict__ agg2,
                            const float* __restrict__ wr2, const float* __restrict__ bias2,
                            const float* __restrict__ fc1w, const float* __restrict__ fc1b,
                            const float* __restrict__ fc2w, const float* __restrict__ fc2b,
                            float* __restrict__ out) {
    __shared__ __align__(16) float h1sh[4][TNB][32];
    __shared__ __align__(16) float h2sh[4][TNB][64];
    __shared__ __align__(16) float h3sh[4][TNB][132];   // +4 pad
    __shared__ __align__(16) float wTsh[10][132];       // fc2w transposed
    int tid = threadIdx.x;
    int wv = tid >> 6, lane = tid & 63;

    for (int t = tid; t < 1280; t += 256) {
        int k = t / 10, j = t - k * 10;
        wTsh[j][k] = fc2w[t];
    }
    __syncthreads();   // only barrier; everything below is wave-local

    int nb = blockIdx.x * (4 * TNB) + wv * TNB;

    {
        const float2* hp = (const float2*)(h1 + (size_t)nb * 32);
        ((float2*)&h1sh[wv][0][0])[lane] = hp[lane];
    }

    float b2v = bias2[lane];
    float ac0 = agg2[(size_t)(nb + 0) * 64 + lane];
    float ac1 = agg2[(size_t)(nb + 1) * 64 + lane];
    float ac2 = agg2[(size_t)(nb + 2) * 64 + lane];
    float ac3 = agg2[(size_t)(nb + 3) * 64 + lane];
    ac0 = (ac0 == -FLT_MAX ? 0.f : ac0) + b2v;
    ac1 = (ac1 == -FLT_MAX ? 0.f : ac1) + b2v;
    ac2 = (ac2 == -FLT_MAX ? 0.f : ac2) + b2v;
    ac3 = (ac3 == -FLT_MAX ? 0.f : ac3) + b2v;
#pragma unroll 8
    for (int i = 0; i < 32; ++i) {
        float w = wr2[i * 64 + lane];
        ac0 = fmaf(h1sh[wv][0][i], w, ac0);
        ac1 = fmaf(h1sh[wv][1][i], w, ac1);
        ac2 = fmaf(h1sh[wv][2][i], w, ac2);
        ac3 = fmaf(h1sh[wv][3][i], w, ac3);
    }
    h2sh[wv][0][lane] = elu_f(ac0);
    h2sh[wv][1][lane] = elu_f(ac1);
    h2sh[wv][2][lane] = elu_f(ac2);
    h2sh[wv][3][lane] = elu_f(ac3);

    float fb1 = fc1b[lane], fb2 = fc1b[64 + lane];
    float p0 = fb1, p1 = fb1, p2 = fb1, p3 = fb1;
    float q0 = fb2, q1 = fb2, q2 = fb2, q3 = fb2;
#pragma unroll 2
    for (int k4 = 0; k4 < 16; ++k4) {
        int k = k4 * 4;
        float wA0 = fc1w[(k + 0) * 128 + lane];
        float wB0 = fc1w[(k + 0) * 128 + 64 + lane];
        float wA1 = fc1w[(k + 1) * 128 + lane];
        float wB1 = fc1w[(k + 1) * 128 + 64 + lane];
        float wA2 = fc1w[(k + 2) * 128 + lane];
        float wB2 = fc1w[(k + 2) * 128 + 64 + lane];
        float wA3 = fc1w[(k + 3) * 128 + lane];
        float wB3 = fc1w[(k + 3) * 128 + 64 + lane];
        float4 g0 = ((const float4*)h2sh[wv][0])[k4];
        float4 g1 = ((const float4*)h2sh[wv][1])[k4];
        float4 g2 = ((const float4*)h2sh[wv][2])[k4];
        float4 g3 = ((const float4*)h2sh[wv][3])[k4];
        p0 = fmaf(g0.x, wA0, p0); p0 = fmaf(g0.y, wA1, p0);
        p0 = fmaf(g0.z, wA2, p0); p0 = fmaf(g0.w, wA3, p0);
        q0 = fmaf(g0.x, wB0, q0); q0 = fmaf(g0.y, wB1, q0);
        q0 = fmaf(g0.z, wB2, q0); q0 = fmaf(g0.w, wB3, q0);
        p1 = fmaf(g1.x, wA0, p1); p1 = fmaf(g1.y, wA1, p1);
        p1 = fmaf(g1.z, wA2, p1); p1 = fmaf(g1.w, wA3, p1);
        q1 = fmaf(g1.x, wB0, q1); q1 = fmaf(g1.y, wB1, q1);
        q1 = fmaf(g1.z, wB2, q1); q1 = fmaf(g1.w, wB3, q1);
        p2 = fmaf(g2.x, wA0, p2); p2 = fmaf(g2.y, wA1, p2);
        p2 = fmaf(g2.z, wA2, p2); p2 = fmaf(g2.w, wA3, p2);
        q2 = fmaf(g2.x, wB0, q2); q2 = fmaf(g2.y, wB1, q2);
        q2 = fmaf(g2.z, wB2, q2); q2 = fmaf(g2.w, wB3, q2);
        p3 = fmaf(g3.x, wA0, p3); p3 = fmaf(g3.y, wA1, p3);
        p3 = fmaf(g3.z, wA2, p3); p3 = fmaf(g3.w, wA3, p3);
        q3 = fmaf(g3.x, wB0, q3); q3 = fmaf(g3.y, wB1, q3);
        q3 = fmaf(g3.z, wB2, q3); q3 = fmaf(g3.w, wB3, q3);
    }
    h3sh[wv][0][lane] = elu_f(p0); h3sh[wv][0][64 + lane] = elu_f(q0);
    h3sh[wv][1][lane] = elu_f(p1); h3sh[wv][1][64 + lane] = elu_f(q1);
    h3sh[wv][2][lane] = elu_f(p2); h3sh[wv][2][64 + lane] = elu_f(q2);
    h3sh[wv][3][lane] = elu_f(p3); h3sh[wv][3][64 + lane] = elu_f(q3);

    {
        int n = lane >> 4, j = lane & 15;
        bool act = j < 10;
        int jc = act ? j : 0;
        float a = fc2b[jc];
        const float4* h3v = (const float4*)h3sh[wv][n];
        const float4* wv4 = (const float4*)wTsh[jc];
#pragma unroll
        for (int q = 0; q < 32; ++q) {
            float4 h = h3v[q];
            float4 w = wv4[q];
            a = fmaf(h.x, w.x, a);
            a = fmaf(h.y, w.y, a);
            a = fmaf(h.z, w.z, a);
            a = fmaf(h.w, w.w, a);
        }
        float lm = act ? a : -FLT_MAX;
        lm = fmaxf(lm, __shfl_xor(lm, 1, 16));
        lm = fmaxf(lm, __shfl_xor(lm, 2, 16));
        lm = fmaxf(lm, __shfl_xor(lm, 4, 16));
        lm = fmaxf(lm, __shfl_xor(lm, 8, 16));
        float ls = act ? expf(a - lm) : 0.f;
        ls += __shfl_xor(ls, 1, 16);
        ls += __shfl_xor(ls, 2, 16);
        ls += __shfl_xor(ls, 4, 16);
        ls += __shfl_xor(ls, 8, 16);
        if (act) out[(size_t)(nb + n) * 10 + j] = a - lm - logf(ls);
    }
}

extern "C" void kernel_launch(void* const* d_in, const int* in_sizes, int n_in,
                              void* d_out, int out_size, void* d_ws, size_t ws_size,
                              hipStream_t stream) {
    const float* x     = (const float*)d_in[0];
    const int*   eidx  = (const int*)d_in[1];
    const float* ea    = (const float*)d_in[2];
    const float* w1a   = (const float*)d_in[3];
    const float* b1a   = (const float*)d_in[4];
    const float* w1b   = (const float*)d_in[5];
    const float* b1b   = (const float*)d_in[6];
    const float* wr1   = (const float*)d_in[7];
    const float* bias1 = (const float*)d_in[8];
    const float* w2a   = (const float*)d_in[9];
    const float* b2a   = (const float*)d_in[10];
    const float* w2b   = (const float*)d_in[11];
    const float* b2b   = (const float*)d_in[12];
    const float* wr2   = (const float*)d_in[13];
    const float* bias2 = (const float*)d_in[14];
    const float* fc1w  = (const float*)d_in[15];
    const float* fc1b  = (const float*)d_in[16];
    const float* fc2w  = (const float*)d_in[17];
    const float* fc2b  = (const float*)d_in[18];

    const int N = in_sizes[0] / 16;   // 20000
    const int E = in_sizes[2];        // 100000
    const int* src = eidx;
    const int* tgt = eidx + E;

    const int cap1 = ((E + 26 * (CH1 - 1)) + CH1 - 1) / CH1 * CH1;
    const int cap2 = ((E + 26 * (CH2 - 1)) + CH2 - 1) / CH2 * CH2;

    float* ws = (float*)d_ws;
    size_t off = 0;
    int*   hist = (int*)(ws + off);   off += 64;   // hist+cur contiguous: 512B memset
    int*   cur  = (int*)(ws + off);   off += 64;
    int*   segp = (int*)(ws + off);   off += E;
    int*   ord1 = (int*)(ws + off);   off += cap1; // ord1/ord2 contiguous
    int*   ord2 = (int*)(ws + off);   off += cap2;
    float* U1   = ws + off;           off += 26 * 512;
    float* V1   = ws + off;           off += 26 * 512;
    float* U2   = ws + off;           off += 26 * 2048;
    float* V2   = ws + off;           off += 26 * 2048;
    float* AGG1 = ws + off;           off += (size_t)N * 32;  // AGG1/AGG2 contiguous
    float* AGG2 = ws + off;           off += (size_t)N * 64;
    float* H1b  = ws + off;           off += (size_t)N * 32;

    const int nAssign = (E + 255) / 256;   // 391

    PrepParams pp;
    pp.ea = ea; pp.w1a = w1a; pp.b1a = b1a; pp.w1b = w1b; pp.b1b = b1b;
    pp.w2a = w2a; pp.b2a = b2a; pp.w2b = w2b; pp.b2b = b2b;
    pp.hist = hist; pp.segp = segp; pp.ord1 = ord1;
    pp.U1 = U1; pp.V1 = V1; pp.U2 = U2; pp.V2 = V2; pp.AGG1 = AGG1;
    pp.N = N; pp.E = E; pp.capSum = cap1 + cap2;

    // 0. hist + cur = 0 (512 B; graph-capturable)
    hipMemsetAsync(hist, 0, 512, stream);
    // 1. fused fill + build_uv + assign_hist
    prep_kernel<<<K1_FILL + K1_UV + nAssign, 256, 0, stream>>>(pp);
    // 2. scatter with in-block scan (scanpad folded in)
    scatter_scan_kernel<<<nAssign, 256, 0, stream>>>(segp, E, hist, cur, ord1, ord2);
    // 3. conv1 edges
    {
        int waves = cap1 / CH1;
        edge1_kernel<<<(waves + 3) / 4, 256, 0, stream>>>(x, src, tgt, ea, ord1, cap1, U1, V1, AGG1);
    }
    // 4. conv1 node update
    node1_kernel<<<(N * 32 + 255) / 256, 256, 0, stream>>>(x, AGG1, wr1, bias1, H1b, N);
    // 5. conv2 edges
    {
        int waves = cap2 / CH2;
        edge2_kernel<<<(waves + 3) / 4, 256, 0, stream>>>(H1b, src, tgt, ea, ord2, cap2, U2, V2, AGG2);
    }
    // 6. fused node2 + fc1 + fc2 + log_softmax
    tail_kernel<<<N / 16, 256, 0, stream>>>(H1b, AGG2, wr2, bias2, fc1w, fc1b, fc2w, fc2b, (float*)d_out);
}

// Round 12
// 190.483 us; speedup vs baseline: 1.1261x; 1.0089x over previous
//
#include <hip/hip_runtime.h>
#include <float.h>
#include <math.h>

// NNConv net: 2x edge-conditioned conv (scalar edge attr) + 2 FC + log_softmax.
// W_e = a_e*U_s + V_s over <=26 breakpoint segments of the scalar edge attr.
// Edges bucketed by segment (chunk-aligned so a wave chunk is single-segment).
// R7: tail 4-nodes/wave loop-order reuse -> 198 us. R8/R9: cooperative fusion
// FALSIFIED (997 us, grid.sync+fences serialize through 8 XCD TCCs).
// R10/R12/R13: every perturbation of the edge bodies (float4 loads, LDS
// staging, CH2=32) tipped the 64-float U/V register cache into scratch
// (allocator/unroll cliff) -> DO NOT PERTURB the R7/R11 edge bodies.
// R11/R14: prep fusion + folded scan + memset + R7 bodies -> 189.7/192.2 us.
// R15: fold node1's root matmul (x@wr1+bias1, edge-independent) into prep as
//      a 4th concurrent block-range section (ROOT1); node1 becomes a pure
//      elementwise fixup+add+elu. Shortens the 5th serial link; touches none
//      of the fragile register structures.

#define NCONST 25
#define CH1 32   // edges per wave chunk, conv1
#define CH2 16   // edges per wave chunk, conv2 (32 spilled in R13; keep 16)
#define PACK_MASK 0x1FFFF  // edge id < 2^17 (E = 100000)
#define TNB 4    // nodes per wave in tail
#define K1_FILL 64
#define K1_UV   260

__device__ __forceinline__ void atomicMaxFloat(float* addr, float val) {
    if (val >= 0.f) atomicMax((int*)addr, __float_as_int(val));
    else            atomicMin((unsigned int*)addr, __float_as_uint(val));
}
__device__ __forceinline__ float readlane_f(float v, int l) {
    return __int_as_float(__builtin_amdgcn_readlane(__float_as_int(v), l));
}
__device__ __forceinline__ float elu_f(float a) {
    return a > 0.f ? a : expm1f(a);
}

struct PrepParams {
    const float *x, *ea;
    const float *w1a, *b1a, *w1b, *b1b, *wr1, *bias1;
    const float *w2a, *b2a, *w2b, *b2b;
    int *hist, *segp, *ord1;               // ord1/ord2 contiguous; fill covers both
    float *U1, *V1, *U2, *V2, *AGG1, *ROOT1;  // AGG1/AGG2 contiguous
    int N, E, capSum, nAssign;
};

// ===== K1: fused {fill aggs/ords, build_uv, assign_hist, root1}. Block role
// by blockIdx range; sections mutually independent (hist pre-zeroed by memset).
__global__ void prep_kernel(PrepParams p) {
    __shared__ float t1[NCONST], t2[NCONST];
    __shared__ int lh[64];
    __shared__ float swa[NCONST], sba[NCONST], stt[NCONST];
    __shared__ int srk[NCONST];
    __shared__ unsigned msk_sh;
    const int bid = blockIdx.x, tid = threadIdx.x;

    if (bid < K1_FILL) {
        int nAgg = p.N * 96, total = nAgg + p.capSum;
        for (int i = bid * 256 + tid; i < total; i += K1_FILL * 256) {
            if (i < nAgg) p.AGG1[i] = -FLT_MAX;
            else p.ord1[i - nAgg] = -1;
        }
    } else if (bid < K1_FILL + K1_UV) {
        int v = bid - K1_FILL;
        int seg = v / 10;
        int bx  = v % 10;
        int conv = (bx < 2) ? 0 : 1;
        const float* wa = conv ? p.w2a : p.w1a;
        const float* ba = conv ? p.b2a : p.b1a;
        if (tid < NCONST) {
            float w = wa[tid], b = ba[tid];
            swa[tid] = w; sba[tid] = b;
            stt[tid] = (w != 0.f) ? (-b / w) : INFINITY;
        }
        __syncthreads();
        if (tid < NCONST) {
            int rk = 0;
            for (int l = 0; l < NCONST; ++l) rk += (stt[l] < stt[tid]) ? 1 : 0;
            srk[tid] = rk;
        }
        __syncthreads();
        if (tid == 0) {
            unsigned m = 0;
            for (int k = 0; k < NCONST; ++k) {
                float w = swa[k];
                bool act = (w > 0.f) ? (seg > srk[k])
                         : (w < 0.f) ? (seg <= srk[k])
                                     : (sba[k] > 0.f);
                if (act) m |= (1u << k);
            }
            msk_sh = m;
        }
        __syncthreads();
        unsigned msk = msk_sh;
        if (conv == 0) {
            int idx = bx * 256 + tid;           // < 512
            float u = 0.f, vv = 0.f;
            for (int k = 0; k < NCONST; ++k)
                if (msk & (1u << k)) { float w = p.w1b[k * 512 + idx]; u = fmaf(swa[k], w, u); vv = fmaf(sba[k], w, vv); }
            vv += p.b1b[idx];
            p.U1[seg * 512 + idx] = u; p.V1[seg * 512 + idx] = vv;
        } else {
            int idx = (bx - 2) * 256 + tid;     // < 2048
            float u = 0.f, vv = 0.f;
            for (int k = 0; k < NCONST; ++k)
                if (msk & (1u << k)) { float w = p.w2b[k * 2048 + idx]; u = fmaf(swa[k], w, u); vv = fmaf(sba[k], w, vv); }
            vv += p.b2b[idx];
            p.U2[seg * 2048 + idx] = u; p.V2[seg * 2048 + idx] = vv;
        }
    } else if (bid < K1_FILL + K1_UV + p.nAssign) {
        if (tid < NCONST) {
            float w = p.w1a[tid]; t1[tid] = (w != 0.f) ? (-p.b1a[tid] / w) : INFINITY;
            float v = p.w2a[tid]; t2[tid] = (v != 0.f) ? (-p.b2a[tid] / v) : INFINITY;
        }
        if (tid < 64) lh[tid] = 0;
        __syncthreads();
        int e = (bid - K1_FILL - K1_UV) * 256 + tid;
        if (e < p.E) {
            float a = p.ea[e];
            int j1 = 0, j2 = 0;
            for (int k = 0; k < NCONST; ++k) { j1 += (t1[k] < a); j2 += (t2[k] < a); }
            p.segp[e] = j1 | (j2 << 8);
            atomicAdd(&lh[j1], 1); atomicAdd(&lh[32 + j2], 1);
        }
        __syncthreads();
        if (tid < 64 && lh[tid]) atomicAdd(&p.hist[tid], lh[tid]);
    } else {
        // ---- root1: ROOT1[n*32+c] = bias1[c] + x[n]@wr1[:,c] (edge-indep) ----
        int idx = (bid - K1_FILL - K1_UV - p.nAssign) * 256 + tid;
        if (idx < p.N * 32) {
            int n = idx >> 5, c = idx & 31;
            float acc = p.bias1[c];
#pragma unroll
            for (int i = 0; i < 16; ++i) acc = fmaf(p.x[n * 16 + i], p.wr1[i * 32 + c], acc);
            p.ROOT1[idx] = acc;
        }
    }
}

// ===== K2: scatter with in-block scan (scanpad folded in).
__global__ void scatter_scan_kernel(const int* __restrict__ segpack, int E,
                                    const int* __restrict__ hist, int* __restrict__ cur,
                                    int* __restrict__ order1, int* __restrict__ order2) {
    __shared__ int h[64], sbase[64], lh[64], lb[64];
    int tid = threadIdx.x;
    if (tid < 64) h[tid] = hist[tid];
    __syncthreads();
    if (tid == 0) {
        int off = 0;
        for (int j = 0; j < 26; ++j) { sbase[j] = off; off += ((h[j] + CH1 - 1) / CH1) * CH1; }
    } else if (tid == 1) {
        int off = 0;
        for (int j = 0; j < 26; ++j) { sbase[32 + j] = off; off += ((h[32 + j] + CH2 - 1) / CH2) * CH2; }
    }
    if (tid < 64) lh[tid] = 0;
    __syncthreads();
    int e = blockIdx.x * 256 + tid;
    bool valid = e < E;
    int j1 = 0, j2 = 0, r1 = 0, r2 = 0;
    if (valid) {
        int pk = segpack[e]; j1 = pk & 0xFF; j2 = pk >> 8;
        r1 = atomicAdd(&lh[j1], 1); r2 = atomicAdd(&lh[32 + j2], 1);
    }
    __syncthreads();
    if (tid < 64 && lh[tid]) lb[tid] = sbase[tid] + atomicAdd(&cur[tid], lh[tid]);
    __syncthreads();
    if (valid) {
        order1[lb[j1] + r1] = (j1 << 17) | e;
        order2[lb[32 + j2] + r2] = (j2 << 17) | e;
    }
}

// ===== edge1: IC=16, OC=32, half-wave per edge (2 edges/iter). R7/R11 body:
// wave-uniform scalar x loads (s_load path), per-lane U/V register cache.
// DO NOT PERTURB: R10/R12/R13 all tipped Ur/Vr into scratch.
__global__ void edge1_kernel(const float* __restrict__ xin, const int* __restrict__ src,
                             const int* __restrict__ tgt, const float* __restrict__ ea,
                             const int* __restrict__ order, int cap,
                             const float* __restrict__ U, const float* __restrict__ V,
                             float* __restrict__ agg) {
    int wid = (blockIdx.x * blockDim.x + threadIdx.x) >> 6;
    int lane = threadIdx.x & 63;
    int base = wid * CH1;
    if (base >= cap) return;
    int pk = order[base + (lane & (CH1 - 1))];
    int p0 = __builtin_amdgcn_readfirstlane(pk);
    if (p0 < 0) return;                        // whole-pad chunk past used region
    int seg = p0 >> 17;
    int ev = (pk < 0) ? 0 : (pk & PACK_MASK);
    int sv = src[ev], tv = tgt[ev];
    float av = ea[ev];
    int half = lane >> 5, c = lane & 31;
    float Ur[16], Vr[16];
    {
        const float* Us = U + seg * 512 + c;
        const float* Vs = V + seg * 512 + c;
#pragma unroll
        for (int i = 0; i < 16; ++i) { Ur[i] = Us[i * 32]; Vr[i] = Vs[i * 32]; }
    }
#pragma unroll
    for (int t = 0; t < CH1; t += 2) {
        int pA = __builtin_amdgcn_readlane(pk, t);
        int pB = __builtin_amdgcn_readlane(pk, t + 1);
        int sA = __builtin_amdgcn_readlane(sv, t);
        int sB = __builtin_amdgcn_readlane(sv, t + 1);
        int tA = __builtin_amdgcn_readlane(tv, t);
        int tB = __builtin_amdgcn_readlane(tv, t + 1);
        float aA = readlane_f(av, t);
        float aB = readlane_f(av, t + 1);
        const float* xA = xin + sA * 16;
        const float* xB = xin + sB * 16;
        float ah = half ? aB : aA;
        int   th = half ? tB : tA;
        int   ph = half ? pB : pA;
        float acc = 0.f;
#pragma unroll
        for (int i = 0; i < 16; ++i) {
            float xi = half ? xB[i] : xA[i];
            acc = fmaf(xi, fmaf(ah, Ur[i], Vr[i]), acc);
        }
        if (ph >= 0) atomicMaxFloat(&agg[th * 32 + c], acc);
    }
}

// ===== edge2: IC=32, OC=64, lane = out channel, A/B edge pair. R7/R11 body.
// DO NOT PERTURB (allocator cliff).
__global__ void edge2_kernel(const float* __restrict__ xin, const int* __restrict__ src,
                             const int* __restrict__ tgt, const float* __restrict__ ea,
                             const int* __restrict__ order, int cap,
                             const float* __restrict__ U, const float* __restrict__ V,
                             float* __restrict__ agg) {
    int wid = (blockIdx.x * blockDim.x + threadIdx.x) >> 6;
    int lane = threadIdx.x & 63;
    int base = wid * CH2;
    if (base >= cap) return;
    int pk = order[base + (lane & (CH2 - 1))];
    int p0 = __builtin_amdgcn_readfirstlane(pk);
    if (p0 < 0) return;
    int seg = p0 >> 17;
    int ev = (pk < 0) ? 0 : (pk & PACK_MASK);
    int sv = src[ev], tv = tgt[ev];
    float av = ea[ev];
    float Ur[32], Vr[32];
    {
        const float* Us = U + seg * 2048 + lane;
        const float* Vs = V + seg * 2048 + lane;
#pragma unroll
        for (int i = 0; i < 32; ++i) { Ur[i] = Us[i * 64]; Vr[i] = Vs[i * 64]; }
    }
#pragma unroll
    for (int t = 0; t < CH2; t += 2) {
        int pA = __builtin_amdgcn_readlane(pk, t);
        int pB = __builtin_amdgcn_readlane(pk, t + 1);
        int sA = __builtin_amdgcn_readlane(sv, t);
        int sB = __builtin_amdgcn_readlane(sv, t + 1);
        int tA = __builtin_amdgcn_readlane(tv, t);
        int tB = __builtin_amdgcn_readlane(tv, t + 1);
        float aA = readlane_f(av, t);
        float aB = readlane_f(av, t + 1);
        const float* xA = xin + sA * 32;
        const float* xB = xin + sB * 32;
        float accA = 0.f, accB = 0.f;
#pragma unroll
        for (int i = 0; i < 32; ++i) {
            accA = fmaf(xA[i], fmaf(aA, Ur[i], Vr[i]), accA);
            accB = fmaf(xB[i], fmaf(aB, Ur[i], Vr[i]), accB);
        }
        if (pA >= 0) atomicMaxFloat(&agg[tA * 64 + lane], accA);
        if (pB >= 0) atomicMaxFloat(&agg[tB * 64 + lane], accB);
    }
}

// ===== node1 (R15): pure elementwise — out = elu( fixup(agg) + ROOT1 ).
__global__ void node1_kernel(const float* __restrict__ agg, const float* __restrict__ root,
                             float* __restrict__ out, int N) {
    int idx = blockIdx.x * blockDim.x + threadIdx.x;
    if (idx >= N * 32) return;
    float v = agg[idx];
    if (v == -FLT_MAX) v = 0.f;
    out[idx] = elu_f(v + root[idx]);
}

// ===== tail: node2 + fc1 + fc2 + log_softmax. R7 body: 4 nodes/wave, zero
// local arrays (register arrays spill under the allocator's pinned budget).
__global__ void tail_kernel(const float* __restrict__ h1, const float* __restrict__ agg2,
                            const float* __restrict__ wr2, const float* __restrict__ bias2,
                            const float* __restrict__ fc1w, const float* __restrict__ fc1b,
                            const float* __restrict__ fc2w, const float* __restrict__ fc2b,
                            float* __restrict__ out) {
    __shared__ __align__(16) float h1sh[4][TNB][32];
    __shared__ __align__(16) float h2sh[4][TNB][64];
    __shared__ __align__(16) float h3sh[4][TNB][132];   // +4 pad
    __shared__ __align__(16) float wTsh[10][132];       // fc2w transposed
    int tid = threadIdx.x;
    int wv = tid >> 6, lane = tid & 63;

    for (int t = tid; t < 1280; t += 256) {
        int k = t / 10, j = t - k * 10;
        wTsh[j][k] = fc2w[t];
    }
    __syncthreads();   // only barrier; everything below is wave-local

    int nb = blockIdx.x * (4 * TNB) + wv * TNB;

    {
        const float2* hp = (const float2*)(h1 + (size_t)nb * 32);
        ((float2*)&h1sh[wv][0][0])[lane] = hp[lane];
    }

    float b2v = bias2[lane];
    float ac0 = agg2[(size_t)(nb + 0) * 64 + lane];
    float ac1 = agg2[(size_t)(nb + 1) * 64 + lane];
    float ac2 = agg2[(size_t)(nb + 2) * 64 + lane];
    float ac3 = agg2[(size_t)(nb + 3) * 64 + lane];
    ac0 = (ac0 == -FLT_MAX ? 0.f : ac0) + b2v;
    ac1 = (ac1 == -FLT_MAX ? 0.f : ac1) + b2v;
    ac2 = (ac2 == -FLT_MAX ? 0.f : ac2) + b2v;
    ac3 = (ac3 == -FLT_MAX ? 0.f : ac3) + b2v;
#pragma unroll 8
    for (int i = 0; i < 32; ++i) {
        float w = wr2[i * 64 + lane];
        ac0 = fmaf(h1sh[wv][0][i], w, ac0);
        ac1 = fmaf(h1sh[wv][1][i], w, ac1);
        ac2 = fmaf(h1sh[wv][2][i], w, ac2);
        ac3 = fmaf(h1sh[wv][3][i], w, ac3);
    }
    h2sh[wv][0][lane] = elu_f(ac0);
    h2sh[wv][1][lane] = elu_f(ac1);
    h2sh[wv][2][lane] = elu_f(ac2);
    h2sh[wv][3][lane] = elu_f(ac3);

    float fb1 = fc1b[lane], fb2 = fc1b[64 + lane];
    float p0 = fb1, p1 = fb1, p2 = fb1, p3 = fb1;
    float q0 = fb2, q1 = fb2, q2 = fb2, q3 = fb2;
#pragma unroll 2
    for (int k4 = 0; k4 < 16; ++k4) {
        int k = k4 * 4;
        float wA0 = fc1w[(k + 0) * 128 + lane];
        float wB0 = fc1w[(k + 0) * 128 + 64 + lane];
        float wA1 = fc1w[(k + 1) * 128 + lane];
        float wB1 = fc1w[(k + 1) * 128 + 64 + lane];
        float wA2 = fc1w[(k + 2) * 128 + lane];
        float wB2 = fc1w[(k + 2) * 128 + 64 + lane];
        float wA3 = fc1w[(k + 3) * 128 + lane];
        float wB3 = fc1w[(k + 3) * 128 + 64 + lane];
        float4 g0 = ((const float4*)h2sh[wv][0])[k4];
        float4 g1 = ((const float4*)h2sh[wv][1])[k4];
        float4 g2 = ((const float4*)h2sh[wv][2])[k4];
        float4 g3 = ((const float4*)h2sh[wv][3])[k4];
        p0 = fmaf(g0.x, wA0, p0); p0 = fmaf(g0.y, wA1, p0);
        p0 = fmaf(g0.z, wA2, p0); p0 = fmaf(g0.w, wA3, p0);
        q0 = fmaf(g0.x, wB0, q0); q0 = fmaf(g0.y, wB1, q0);
        q0 = fmaf(g0.z, wB2, q0); q0 = fmaf(g0.w, wB3, q0);
        p1 = fmaf(g1.x, wA0, p1); p1 = fmaf(g1.y, wA1, p1);
        p1 = fmaf(g1.z, wA2, p1); p1 = fmaf(g1.w, wA3, p1);
        q1 = fmaf(g1.x, wB0, q1); q1 = fmaf(g1.y, wB1, q1);
        q1 = fmaf(g1.z, wB2, q1); q1 = fmaf(g1.w, wB3, q1);
        p2 = fmaf(g2.x, wA0, p2); p2 = fmaf(g2.y, wA1, p2);
        p2 = fmaf(g2.z, wA2, p2); p2 = fmaf(g2.w, wA3, p2);
        q2 = fmaf(g2.x, wB0, q2); q2 = fmaf(g2.y, wB1, q2);
        q2 = fmaf(g2.z, wB2, q2); q2 = fmaf(g2.w, wB3, q2);
        p3 = fmaf(g3.x, wA0, p3); p3 = fmaf(g3.y, wA1, p3);
        p3 = fmaf(g3.z, wA2, p3); p3 = fmaf(g3.w, wA3, p3);
        q3 = fmaf(g3.x, wB0, q3); q3 = fmaf(g3.y, wB1, q3);
        q3 = fmaf(g3.z, wB2, q3); q3 = fmaf(g3.w, wB3, q3);
    }
    h3sh[wv][0][lane] = elu_f(p0); h3sh[wv][0][64 + lane] = elu_f(q0);
    h3sh[wv][1][lane] = elu_f(p1); h3sh[wv][1][64 + lane] = elu_f(q1);
    h3sh[wv][2][lane] = elu_f(p2); h3sh[wv][2][64 + lane] = elu_f(q2);
    h3sh[wv][3][lane] = elu_f(p3); h3sh[wv][3][64 + lane] = elu_f(q3);

    {
        int n = lane >> 4, j = lane & 15;
        bool act = j < 10;
        int jc = act ? j : 0;
        float a = fc2b[jc];
        const float4* h3v = (const float4*)h3sh[wv][n];
        const float4* wv4 = (const float4*)wTsh[jc];
#pragma unroll
        for (int q = 0; q < 32; ++q) {
            float4 h = h3v[q];
            float4 w = wv4[q];
            a = fmaf(h.x, w.x, a);
            a = fmaf(h.y, w.y, a);
            a = fmaf(h.z, w.z, a);
            a = fmaf(h.w, w.w, a);
        }
        float lm = act ? a : -FLT_MAX;
        lm = fmaxf(lm, __shfl_xor(lm, 1, 16));
        lm = fmaxf(lm, __shfl_xor(lm, 2, 16));
        lm = fmaxf(lm, __shfl_xor(lm, 4, 16));
        lm = fmaxf(lm, __shfl_xor(lm, 8, 16));
        float ls = act ? expf(a - lm) : 0.f;
        ls += __shfl_xor(ls, 1, 16);
        ls += __shfl_xor(ls, 2, 16);
        ls += __shfl_xor(ls, 4, 16);
        ls += __shfl_xor(ls, 8, 16);
        if (act) out[(size_t)(nb + n) * 10 + j] = a - lm - logf(ls);
    }
}

extern "C" void kernel_launch(void* const* d_in, const int* in_sizes, int n_in,
                              void* d_out, int out_size, void* d_ws, size_t ws_size,
                              hipStream_t stream) {
    const float* x     = (const float*)d_in[0];
    const int*   eidx  = (const int*)d_in[1];
    const float* ea    = (const float*)d_in[2];
    const float* w1a   = (const float*)d_in[3];
    const float* b1a   = (const float*)d_in[4];
    const float* w1b   = (const float*)d_in[5];
    const float* b1b   = (const float*)d_in[6];
    const float* wr1   = (const float*)d_in[7];
    const float* bias1 = (const float*)d_in[8];
    const float* w2a   = (const float*)d_in[9];
    const float* b2a   = (const float*)d_in[10];
    const float* w2b   = (const float*)d_in[11];
    const float* b2b   = (const float*)d_in[12];
    const float* wr2   = (const float*)d_in[13];
    const float* bias2 = (const float*)d_in[14];
    const float* fc1w  = (const float*)d_in[15];
    const float* fc1b  = (const float*)d_in[16];
    const float* fc2w  = (const float*)d_in[17];
    const float* fc2b  = (const float*)d_in[18];

    const int N = in_sizes[0] / 16;   // 20000
    const int E = in_sizes[2];        // 100000
    const int* src = eidx;
    const int* tgt = eidx + E;

    const int cap1 = ((E + 26 * (CH1 - 1)) + CH1 - 1) / CH1 * CH1;
    const int cap2 = ((E + 26 * (CH2 - 1)) + CH2 - 1) / CH2 * CH2;

    float* ws = (float*)d_ws;
    size_t off = 0;
    int*   hist = (int*)(ws + off);   off += 64;   // hist+cur contiguous: 512B memset
    int*   cur  = (int*)(ws + off);   off += 64;
    int*   segp = (int*)(ws + off);   off += E;
    int*   ord1 = (int*)(ws + off);   off += cap1; // ord1/ord2 contiguous
    int*   ord2 = (int*)(ws + off);   off += cap2;
    float* U1   = ws + off;           off += 26 * 512;
    float* V1   = ws + off;           off += 26 * 512;
    float* U2   = ws + off;           off += 26 * 2048;
    float* V2   = ws + off;           off += 26 * 2048;
    float* AGG1 = ws + off;           off += (size_t)N * 32;  // AGG1/AGG2 contiguous
    float* AGG2 = ws + off;           off += (size_t)N * 64;
    float* H1b  = ws + off;           off += (size_t)N * 32;
    float* ROOT1 = ws + off;          off += (size_t)N * 32;

    const int nAssign = (E + 255) / 256;       // 391
    const int nRoot   = (N * 32 + 255) / 256;  // 2500

    PrepParams pp;
    pp.x = x; pp.ea = ea;
    pp.w1a = w1a; pp.b1a = b1a; pp.w1b = w1b; pp.b1b = b1b;
    pp.wr1 = wr1; pp.bias1 = bias1;
    pp.w2a = w2a; pp.b2a = b2a; pp.w2b = w2b; pp.b2b = b2b;
    pp.hist = hist; pp.segp = segp; pp.ord1 = ord1;
    pp.U1 = U1; pp.V1 = V1; pp.U2 = U2; pp.V2 = V2; pp.AGG1 = AGG1; pp.ROOT1 = ROOT1;
    pp.N = N; pp.E = E; pp.capSum = cap1 + cap2; pp.nAssign = nAssign;

    // 0. hist + cur = 0 (512 B; graph-capturable)
    hipMemsetAsync(hist, 0, 512, stream);
    // 1. fused fill + build_uv + assign_hist + root1
    prep_kernel<<<K1_FILL + K1_UV + nAssign + nRoot, 256, 0, stream>>>(pp);
    // 2. scatter with in-block scan (scanpad folded in)
    scatter_scan_kernel<<<nAssign, 256, 0, stream>>>(segp, E, hist, cur, ord1, ord2);
    // 3. conv1 edges
    {
        int waves = cap1 / CH1;
        edge1_kernel<<<(waves + 3) / 4, 256, 0, stream>>>(x, src, tgt, ea, ord1, cap1, U1, V1, AGG1);
    }
    // 4. conv1 node update (elementwise: fixup + root + elu)
    node1_kernel<<<(N * 32 + 255) / 256, 256, 0, stream>>>(AGG1, ROOT1, H1b, N);
    // 5. conv2 edges
    {
        int waves = cap2 / CH2;
        edge2_kernel<<<(waves + 3) / 4, 256, 0, stream>>>(H1b, src, tgt, ea, ord2, cap2, U2, V2, AGG2);
    }
    // 6. fused node2 + fc1 + fc2 + log_softmax
    tail_kernel<<<N / 16, 256, 0, stream>>>(H1b, AGG2, wr2, bias2, fc1w, fc1b, fc2w, fc2b, (float*)d_out);
}